// Round 8
// baseline (444.923 us; speedup 1.0000x reference)
//
#include <hip/hip_runtime.h>
#include <hip/hip_cooperative_groups.h>

namespace cg = cooperative_groups;

#define NNODES 50000
#define NEDGES 200000
#define NSCANB ((NNODES + 255) / 256)   // 196 scan blocks

typedef short  bf16x8 __attribute__((ext_vector_type(8)));
typedef float  f32x4  __attribute__((ext_vector_type(4)));
typedef unsigned int u32x4 __attribute__((ext_vector_type(4)));

__device__ __forceinline__ unsigned short f2bf(float f) {
    union { float f; unsigned int u; } c; c.f = f;
    unsigned int r = c.u + 0x7fffu + ((c.u >> 16) & 1u);
    return (unsigned short)(r >> 16);
}
__device__ __forceinline__ float bflo(unsigned int v) {
    union { unsigned int u; float f; } c; c.u = v << 16;
    return c.f;
}
__device__ __forceinline__ float bfhi(unsigned int v) {
    union { unsigned int u; float f; } c; c.u = v & 0xffff0000u;
    return c.f;
}

// ---------------- cooperative graph build: zero+count+scan+scatter ----------
// Replaces memset + edge-count + scanA + scanC2 + scatter (4 launches + memset
// -> 1 cooperative launch, 196 blocks co-resident, 4 grid syncs).
__global__ __launch_bounds__(256) void k_graph(const int* __restrict__ ei,
                                               int* __restrict__ deg,
                                               int* __restrict__ rs,
                                               int* __restrict__ cursor,
                                               int* __restrict__ partials,
                                               int* __restrict__ srcs) {
    cg::grid_group grid = cg::this_grid();
    __shared__ int sm[256];
    const int t = threadIdx.x, b = blockIdx.x;
    const int gtid = b * 256 + t;
    const int GS = gridDim.x * 256;

    // phase 0: zero deg
    for (int i = gtid; i < NNODES; i += GS) deg[i] = 0;
    grid.sync();
    // phase 1: count in-degrees
    for (int e = gtid; e < NEDGES; e += GS) atomicAdd(&deg[ei[NEDGES + e]], 1);
    grid.sync();
    // phase 2: block-local exclusive scan (196*256 = 50176 covers NNODES)
    const int i = gtid;
    int v = (i < NNODES) ? deg[i] : 0;
    sm[t] = v;
    __syncthreads();
#pragma unroll
    for (int off = 1; off < 256; off <<= 1) {
        int u = (t >= off) ? sm[t - off] : 0;
        __syncthreads();
        sm[t] += u;
        __syncthreads();
    }
    const int local = sm[t] - v;
    if (t == 255) partials[b] = sm[255];
    grid.sync();
    // phase 3: add prefix of partials, write rs + cursor
    sm[t] = (t < b && t < NSCANB) ? partials[t] : 0;
    __syncthreads();
#pragma unroll
    for (int off = 128; off; off >>= 1) {
        if (t < off) sm[t] += sm[t + off];
        __syncthreads();
    }
    {
        int off0 = sm[0];
        if (i < NNODES) { int rv = local + off0; rs[i] = rv; cursor[i] = rv; }
        if (i == 0) rs[NNODES] = NEDGES;
    }
    grid.sync();
    // phase 4: scatter src indices into CSR order
    for (int e = gtid; e < NEDGES; e += GS) {
        int d = ei[NEDGES + e];
        int p = atomicAdd(&cursor[d], 1);
        srcs[p] = ei[e];
    }
}

// ---------------- prep: weight transpose + x -> bf16 (wide grid-stride) -----
#define PREP_B1 (256 * 1024)
#define PREP_B2 (64 * 512)
#define PREP_XC (NNODES * 64)
__global__ __launch_bounds__(256) void k_prep(const float* __restrict__ x,
                                              const float* __restrict__ W1_rel,
                                              const float* __restrict__ W1_root,
                                              const float* __restrict__ W2_rel,
                                              const float* __restrict__ W2_root,
                                              unsigned short* __restrict__ Bt1,
                                              unsigned short* __restrict__ Bt2,
                                              unsigned short* __restrict__ xb) {
    const int gtid = blockIdx.x * 256 + threadIdx.x;
    const int GS = gridDim.x * 256;
    for (int i = gtid; i < PREP_B1; i += GS) {
        int n = i >> 10, k = i & 1023;
        float v = (k < 512) ? W1_rel[k * 256 + n] : W1_root[(k - 512) * 256 + n];
        Bt1[i] = f2bf(v);
    }
    for (int i = gtid; i < PREP_B2; i += GS) {
        int n = i >> 9, k = i & 511;
        float v = (k < 256) ? W2_rel[k * 64 + n] : W2_root[(k - 256) * 64 + n];
        Bt2[i] = f2bf(v);
    }
    for (int i = gtid; i < PREP_XC; i += GS) {
        int n = i >> 6, c8 = (i & 63) * 8;
        const float* xp = x + (size_t)n * 512 + c8;
        float4 a = *(const float4*)xp;
        float4 bb = *(const float4*)(xp + 4);
        unsigned short o[8];
        o[0] = f2bf(a.x); o[1] = f2bf(a.y); o[2] = f2bf(a.z); o[3] = f2bf(a.w);
        o[4] = f2bf(bb.x); o[5] = f2bf(bb.y); o[6] = f2bf(bb.z); o[7] = f2bf(bb.w);
        *(u32x4*)(xb + (size_t)n * 512 + c8) = *(const u32x4*)o;
    }
}

// ---------------- softmax aggregation (layer 1): wave-per-node -------------
__global__ __launch_bounds__(256) void k_agg1(const unsigned short* __restrict__ xb,
                                              const int* __restrict__ rs,
                                              const int* __restrict__ srcs,
                                              unsigned short* __restrict__ AggBuf) {
    int wv = threadIdx.x >> 6;
    int lane = threadIdx.x & 63;
    int n = blockIdx.x * 4 + wv;
    int e0 = rs[n], e1 = rs[n + 1];
    float nu[8], de[8];
#pragma unroll
    for (int j = 0; j < 8; ++j) { nu[j] = 0.f; de[j] = 0.f; }

    auto accum = [&](u32x4 r) {
#pragma unroll
        for (int p = 0; p < 4; ++p) {
            float v0 = bflo(r[p]), v1 = bfhi(r[p]);
            float E0 = __expf(v0), E1 = __expf(v1);
            de[2 * p] += E0; nu[2 * p] += E0 * v0;
            de[2 * p + 1] += E1; nu[2 * p + 1] += E1 * v1;
        }
    };

    int e = e0;
    for (; e + 3 < e1; e += 4) {
        int s0 = srcs[e], s1 = srcs[e + 1], s2 = srcs[e + 2], s3 = srcs[e + 3];
        u32x4 r0 = *(const u32x4*)(xb + (size_t)s0 * 512 + lane * 8);
        u32x4 r1 = *(const u32x4*)(xb + (size_t)s1 * 512 + lane * 8);
        u32x4 r2 = *(const u32x4*)(xb + (size_t)s2 * 512 + lane * 8);
        u32x4 r3 = *(const u32x4*)(xb + (size_t)s3 * 512 + lane * 8);
        accum(r0); accum(r1); accum(r2); accum(r3);
    }
    if (e + 1 < e1) {
        int s0 = srcs[e], s1 = srcs[e + 1];
        u32x4 r0 = *(const u32x4*)(xb + (size_t)s0 * 512 + lane * 8);
        u32x4 r1 = *(const u32x4*)(xb + (size_t)s1 * 512 + lane * 8);
        accum(r0); accum(r1);
        e += 2;
    }
    if (e < e1) {
        u32x4 r0 = *(const u32x4*)(xb + (size_t)srcs[e] * 512 + lane * 8);
        accum(r0);
    }
    unsigned short o[8];
#pragma unroll
    for (int j = 0; j < 8; ++j) o[j] = f2bf(nu[j] / fmaxf(de[j], 1e-16f));
    *(u32x4*)(AggBuf + (size_t)n * 512 + lane * 8) = *(const u32x4*)o;
}

// ---------------- sum aggregation (layer 2): wave-per-node ------------------
__global__ __launch_bounds__(256) void k_agg2(const int* __restrict__ rs,
                                              const int* __restrict__ srcs,
                                              const unsigned short* __restrict__ H1,
                                              unsigned short* __restrict__ Seg) {
    int wv = threadIdx.x >> 6;
    int lane = threadIdx.x & 63;
    int n = blockIdx.x * 4 + wv;
    int e0 = rs[n], e1 = rs[n + 1];
    float a[4] = {0.f, 0.f, 0.f, 0.f};

    auto accum = [&](uint2 r) {
        a[0] += bflo(r.x); a[1] += bfhi(r.x);
        a[2] += bflo(r.y); a[3] += bfhi(r.y);
    };

    int e = e0;
    for (; e + 3 < e1; e += 4) {
        int s0 = srcs[e], s1 = srcs[e + 1], s2 = srcs[e + 2], s3 = srcs[e + 3];
        uint2 r0 = *(const uint2*)(H1 + (size_t)s0 * 256 + lane * 4);
        uint2 r1 = *(const uint2*)(H1 + (size_t)s1 * 256 + lane * 4);
        uint2 r2 = *(const uint2*)(H1 + (size_t)s2 * 256 + lane * 4);
        uint2 r3 = *(const uint2*)(H1 + (size_t)s3 * 256 + lane * 4);
        accum(r0); accum(r1); accum(r2); accum(r3);
    }
    if (e + 1 < e1) {
        int s0 = srcs[e], s1 = srcs[e + 1];
        uint2 r0 = *(const uint2*)(H1 + (size_t)s0 * 256 + lane * 4);
        uint2 r1 = *(const uint2*)(H1 + (size_t)s1 * 256 + lane * 4);
        accum(r0); accum(r1);
        e += 2;
    }
    if (e < e1) {
        uint2 r0 = *(const uint2*)(H1 + (size_t)srcs[e] * 256 + lane * 4);
        accum(r0);
    }
    uint2 o;
    o.x = (unsigned int)f2bf(a[0]) | ((unsigned int)f2bf(a[1]) << 16);
    o.y = (unsigned int)f2bf(a[2]) | ((unsigned int)f2bf(a[3]) << 16);
    *(uint2*)(Seg + (size_t)n * 256 + lane * 4) = o;
}

// ---------------- GEMM1: 128x128 tile + counted-vmcnt double-buffer ---------
// Composition of the two validated levers: 128^2 tile (32 MFMA/wave per
// K-step, cost-free vs 64x128 -- R7) x 2-stage counted vmcnt pipeline (the
// only structure that beat 71 us -- R1's 67.3). 8 global_load_lds per thread
// per stage -> vmcnt(8) waits only the PRIOR buffer's loads, issued one full
// 128-MFMA compute phase earlier. LDS 64.5 KB -> 2 blocks/CU.
__global__ __launch_bounds__(256) void k_gemm1(const unsigned short* __restrict__ A1,
                                               const unsigned short* __restrict__ A2,
                                               const unsigned short* __restrict__ Bt,
                                               const int* __restrict__ rs,
                                               const int* __restrict__ srcs,
                                               const float* __restrict__ r1,
                                               const float* __restrict__ r2,
                                               const float* __restrict__ bias,
                                               unsigned short* __restrict__ outp) {
    constexpr int BM = 128, BN = 128, BK = 64;
    __shared__ __align__(16) unsigned short As[2][BM * BK];   // 32 KB
    __shared__ __align__(16) unsigned short Bs[2][BN * BK];   // 32 KB
    __shared__ float s1t[BM];

    const int tid = threadIdx.x;
    const int w = tid >> 6;        // 0..3
    const int lane = tid & 63;
    const int lm = lane & 15;
    const int quad = lane >> 4;
    const int wr = w >> 1;         // 0..1
    const int wc = w & 1;          // 0..1
    const int rowbase = blockIdx.y * BM;
    const int colbase = blockIdx.x * BN;
    const int wrow = wr * 64;
    const int wcol = wc * 64;

    const int rsub = lane >> 3;
    const int csw = (lane & 7) ^ rsub;

    f32x4 acc[4][4];
#pragma unroll
    for (int mi = 0; mi < 4; ++mi)
#pragma unroll
        for (int ni = 0; ni < 4; ++ni) acc[mi][ni] = (f32x4){0.f, 0.f, 0.f, 0.f};

    // 8 global_load_lds per thread per stage (4 A + 4 B)
    auto stage = [&](unsigned short* Asb, unsigned short* Bsb, int kt) {
        const unsigned short* Ab = (kt < 512) ? A1 : A2;
        int kof = (kt < 512) ? kt : kt - 512;
#pragma unroll
        for (int l = 0; l < 4; ++l) {
            int r = w * 32 + l * 8;
            int gr = rowbase + r + rsub;
            if (gr >= NNODES) gr = NNODES - 1;
            const unsigned short* gp = Ab + (size_t)gr * 512 + kof + csw * 8;
            __builtin_amdgcn_global_load_lds(
                (const __attribute__((address_space(1))) void*)gp,
                (__attribute__((address_space(3))) void*)(Asb + r * BK), 16, 0, 0);
        }
#pragma unroll
        for (int l = 0; l < 4; ++l) {
            int r = w * 32 + l * 8;
            const unsigned short* gp = Bt + (size_t)(colbase + r + rsub) * 1024 + kt + csw * 8;
            __builtin_amdgcn_global_load_lds(
                (const __attribute__((address_space(1))) void*)gp,
                (__attribute__((address_space(3))) void*)(Bsb + r * BK), 16, 0, 0);
        }
    };

    auto compute = [&](const unsigned short* Asb, const unsigned short* Bsb) {
#pragma unroll
        for (int kk = 0; kk < BK; kk += 32) {
            const int kidx = (kk >> 3) + quad;
            const int phys = kidx ^ (lm & 7);
            bf16x8 af[4], bfr[4];
#pragma unroll
            for (int mi = 0; mi < 4; ++mi)
                af[mi] = __builtin_bit_cast(bf16x8,
                    *(const u32x4*)(Asb + (wrow + mi * 16 + lm) * BK + phys * 8));
#pragma unroll
            for (int ni = 0; ni < 4; ++ni)
                bfr[ni] = __builtin_bit_cast(bf16x8,
                    *(const u32x4*)(Bsb + (wcol + ni * 16 + lm) * BK + phys * 8));
#pragma unroll
            for (int mi = 0; mi < 4; ++mi)
#pragma unroll
                for (int ni = 0; ni < 4; ++ni)
                    acc[mi][ni] = __builtin_amdgcn_mfma_f32_16x16x32_bf16(
                        af[mi], bfr[ni], acc[mi][ni], 0, 0, 0);
        }
    };

    stage(As[0], Bs[0], 0);
#pragma unroll 1
    for (int t = 0; t < 16; t += 2) {
        // phase A: compute buf0 (staged last phase), prefetch buf1
        stage(As[1], Bs[1], (t + 1) * BK);
        asm volatile("s_waitcnt vmcnt(8)" ::: "memory");  // buf0's 8 loads done
        __builtin_amdgcn_s_barrier();
        __builtin_amdgcn_sched_barrier(0);
        compute(As[0], Bs[0]);
        __builtin_amdgcn_s_barrier();
        // phase B: compute buf1, prefetch buf0 (unless last tile)
        if (t + 2 < 16) {
            stage(As[0], Bs[0], (t + 2) * BK);
            asm volatile("s_waitcnt vmcnt(8)" ::: "memory");
        } else {
            asm volatile("s_waitcnt vmcnt(0)" ::: "memory");
        }
        __builtin_amdgcn_s_barrier();
        __builtin_amdgcn_sched_barrier(0);
        compute(As[1], Bs[1]);
        __builtin_amdgcn_s_barrier();
    }

    // per-row index softmax (threads 0..127, one row each)
    if (tid < BM) {
        int grow = rowbase + tid;
        float r_ = 0.f;
        if (grow < NNODES) {
            int e0 = rs[grow], e1 = rs[grow + 1];
            float m = -INFINITY, d = 0.f, q = 0.f;
            for (int e = e0; e < e1; ++e) {
                float v = (float)srcs[e];
                float nm = fmaxf(m, v);
                float sc = __expf(m - nm), ee = __expf(v - nm);
                d = d * sc + ee;
                q = q * sc + ee * v;
                m = nm;
            }
            r_ = q / fmaxf(d, 1e-16f);
        }
        s1t[tid] = r_;
    }
    __syncthreads();

#pragma unroll
    for (int ni = 0; ni < 4; ++ni) {
        int gc = colbase + wcol + ni * 16 + lm;
        float r1v = r1[gc], r2v = r2[gc], bv = bias[gc];
#pragma unroll
        for (int mi = 0; mi < 4; ++mi) {
#pragma unroll
            for (int r = 0; r < 4; ++r) {
                int lrow = wrow + mi * 16 + quad * 4 + r;
                int grow = rowbase + lrow;
                if (grow < NNODES) {
                    float v = acc[mi][ni][r] + s1t[lrow] * r1v + (float)grow * r2v + bv;
                    v = (v >= 0.f) ? v : 0.01f * v;
                    outp[(size_t)grow * 256 + gc] = f2bf(v);
                }
            }
        }
    }
}

// ---------------- GEMM2 + fused head: 64x64 tile, split-A [Seg|H1] ----------
// R0/R4 single-buffered form (known-good).
__global__ __launch_bounds__(256) void k_gemm2h(const unsigned short* __restrict__ A1,
                                                const unsigned short* __restrict__ A2,
                                                const unsigned short* __restrict__ Bt,
                                                const int* __restrict__ rs,
                                                const int* __restrict__ srcs,
                                                const float* __restrict__ r1,
                                                const float* __restrict__ r2,
                                                const float* __restrict__ bias,
                                                const float* __restrict__ Wp,
                                                const float* __restrict__ bp,
                                                const float* __restrict__ Wr,
                                                const float* __restrict__ br,
                                                float* __restrict__ out) {
    constexpr int BM = 64, BN = 64, BK = 64;
    __shared__ __align__(16) unsigned short As[BM * BK];
    __shared__ __align__(16) unsigned short Bs[BN * BK];
    __shared__ float h2t[BM * 65];
    __shared__ float s1t[BM];

    const int tid = threadIdx.x;
    const int w = tid >> 6;
    const int lane = tid & 63;
    const int lm = lane & 15;
    const int quad = lane >> 4;
    const int rowbase = blockIdx.x * BM;
    const int wrow = w * 16;

    const int rsub = lane >> 3;
    const int csw = (lane & 7) ^ rsub;

    f32x4 acc[4];
#pragma unroll
    for (int ni = 0; ni < 4; ++ni) acc[ni] = (f32x4){0.f, 0.f, 0.f, 0.f};

    for (int kt = 0; kt < 512; kt += BK) {
        const unsigned short* Ab = (kt < 256) ? A1 : A2;
        int kof = (kt < 256) ? kt : kt - 256;
#pragma unroll
        for (int l = 0; l < 2; ++l) {
            int r = w * 16 + l * 8;
            int gr = rowbase + r + rsub;
            if (gr >= NNODES) gr = NNODES - 1;
            const unsigned short* gp = Ab + (size_t)gr * 256 + kof + csw * 8;
            __builtin_amdgcn_global_load_lds(
                (const __attribute__((address_space(1))) void*)gp,
                (__attribute__((address_space(3))) void*)(As + r * BK), 16, 0, 0);
        }
#pragma unroll
        for (int l = 0; l < 2; ++l) {
            int r = w * 16 + l * 8;
            const unsigned short* gp = Bt + (size_t)(r + rsub) * 512 + kt + csw * 8;
            __builtin_amdgcn_global_load_lds(
                (const __attribute__((address_space(1))) void*)gp,
                (__attribute__((address_space(3))) void*)(Bs + r * BK), 16, 0, 0);
        }
        __syncthreads();
#pragma unroll
        for (int kk = 0; kk < BK; kk += 32) {
            const int kidx = (kk >> 3) + quad;
            const int phys = kidx ^ (lm & 7);
            bf16x8 af;
            af = __builtin_bit_cast(bf16x8,
                *(const u32x4*)(As + (wrow + lm) * BK + phys * 8));
            bf16x8 bfr[4];
#pragma unroll
            for (int ni = 0; ni < 4; ++ni)
                bfr[ni] = __builtin_bit_cast(bf16x8,
                    *(const u32x4*)(Bs + (ni * 16 + lm) * BK + phys * 8));
#pragma unroll
            for (int ni = 0; ni < 4; ++ni)
                acc[ni] = __builtin_amdgcn_mfma_f32_16x16x32_bf16(
                    af, bfr[ni], acc[ni], 0, 0, 0);
        }
        __syncthreads();
    }

    // per-row index sum
    if (tid < BM) {
        int grow = rowbase + tid;
        float si = 0.f;
        if (grow < NNODES) {
            int e0 = rs[grow], e1 = rs[grow + 1];
            for (int e = e0; e < e1; ++e) si += (float)srcs[e];
        }
        s1t[tid] = si;
    }
    __syncthreads();

    // epilogue -> LDS h2 tile
#pragma unroll
    for (int ni = 0; ni < 4; ++ni) {
        int gc = ni * 16 + lm;
        float r1v = r1[gc], r2v = r2[gc], bv = bias[gc];
#pragma unroll
        for (int r = 0; r < 4; ++r) {
            int lrow = wrow + quad * 4 + r;
            int grow = rowbase + lrow;
            float v = acc[ni][r] + s1t[lrow] * r1v + (float)grow * r2v + bv;
            v = (v >= 0.f) ? v : 0.01f * v;
            h2t[lrow * 65 + gc] = v;
        }
    }
    __syncthreads();

    // head: threads 0..63, one row each
    if (tid < BM) {
        int grow = rowbase + tid;
        if (grow < NNODES) {
            const float* hv = h2t + tid * 65;
            float idx = (float)grow;
            float p0 = 0.f, p1 = 0.f, p2 = 0.f;
            float r0 = 0.f, r1a = 0.f, r2a = 0.f, r3 = 0.f;
#pragma unroll 8
            for (int c = 0; c < 64; ++c) {
                float v = hv[c];
                p0 += v * Wp[c * 3 + 0];
                p1 += v * Wp[c * 3 + 1];
                p2 += v * Wp[c * 3 + 2];
                r0 += v * Wr[c * 4 + 0];
                r1a += v * Wr[c * 4 + 1];
                r2a += v * Wr[c * 4 + 2];
                r3 += v * Wr[c * 4 + 3];
            }
            p0 += idx * Wp[64 * 3 + 0] + bp[0];
            p1 += idx * Wp[64 * 3 + 1] + bp[1];
            p2 += idx * Wp[64 * 3 + 2] + bp[2];
            r0 += idx * Wr[64 * 4 + 0] + br[0];
            r1a += idx * Wr[64 * 4 + 1] + br[1];
            r2a += idx * Wr[64 * 4 + 2] + br[2];
            r3 += idx * Wr[64 * 4 + 3] + br[3];
            float nrm = fmaxf(sqrtf(r0 * r0 + r1a * r1a + r2a * r2a + r3 * r3), 1e-12f);
            float* op = out + (size_t)grow * 7;
            op[0] = p0; op[1] = p1; op[2] = p2;
            op[3] = r0 / nrm; op[4] = r1a / nrm; op[5] = r2a / nrm; op[6] = r3 / nrm;
        }
    }
}

extern "C" void kernel_launch(void* const* d_in, const int* in_sizes, int n_in,
                              void* d_out, int out_size, void* d_ws, size_t ws_size,
                              hipStream_t stream) {
    const float* x       = (const float*)d_in[0];
    const float* W1_rel  = (const float*)d_in[1];
    const float* b1      = (const float*)d_in[2];
    const float* W1_root = (const float*)d_in[3];
    const float* W2_rel  = (const float*)d_in[4];
    const float* b2      = (const float*)d_in[5];
    const float* W2_root = (const float*)d_in[6];
    const float* Wp      = (const float*)d_in[7];
    const float* bp      = (const float*)d_in[8];
    const float* Wr      = (const float*)d_in[9];
    const float* br      = (const float*)d_in[10];
    const int*   ei      = (const int*)d_in[11];
    float* out = (float*)d_out;

    char* ws = (char*)d_ws;
    size_t off = 0;
    auto alloc = [&](size_t bytes) {
        size_t o = off;
        off = (off + bytes + 255) & ~(size_t)255;
        return (void*)(ws + o);
    };
    int*   deg       = (int*)alloc(NNODES * 4);
    int*   cursor    = (int*)alloc(NNODES * 4);
    int*   row_start = (int*)alloc((NNODES + 1) * 4);
    int*   srcs      = (int*)alloc(NEDGES * 4);
    int*   partials  = (int*)alloc(NSCANB * 4);
    unsigned short* xb     = (unsigned short*)alloc((size_t)NNODES * 512 * 2);
    unsigned short* AggBuf = (unsigned short*)alloc((size_t)NNODES * 512 * 2);
    unsigned short* H1     = (unsigned short*)alloc((size_t)NNODES * 256 * 2);
    unsigned short* Seg    = (unsigned short*)alloc((size_t)NNODES * 256 * 2);
    unsigned short* Bt1    = (unsigned short*)alloc(256 * 1024 * 2);
    unsigned short* Bt2    = (unsigned short*)alloc(64 * 512 * 2);

    // cooperative graph build (zero+count+scan+scatter in one launch)
    {
        void* kargs[] = {(void*)&ei, (void*)&deg, (void*)&row_start,
                         (void*)&cursor, (void*)&partials, (void*)&srcs};
        hipLaunchCooperativeKernel((void*)k_graph, dim3(NSCANB), dim3(256),
                                   kargs, 0, stream);
    }

    k_prep<<<2048, 256, 0, stream>>>(
        x, W1_rel, W1_root, W2_rel, W2_root, Bt1, Bt2, xb);

    k_agg1<<<NNODES / 4, 256, 0, stream>>>(xb, row_start, srcs, AggBuf);

    // GEMM1: [AggBuf | xb] @ Bt1^T -> H1 (bf16, stride 256). grid (col, row)
    k_gemm1<<<dim3(2, (NNODES + 127) / 128), 256, 0, stream>>>(
        AggBuf, xb, Bt1, row_start, srcs, W1_rel + 512 * 256, W1_root + 512 * 256, b1, H1);

    k_agg2<<<NNODES / 4, 256, 0, stream>>>(row_start, srcs, H1, Seg);

    // GEMM2 + head: [Seg | H1] @ Bt2^T -> out
    k_gemm2h<<<(NNODES + 63) / 64, 256, 0, stream>>>(
        Seg, H1, Bt2, row_start, srcs, W2_rel + 256 * 64, W2_root + 256 * 64, b2,
        Wp, bp, Wr, br, out);
}

// Round 9
// 337.258 us; speedup vs baseline: 1.3192x; 1.3192x over previous
//
#include <hip/hip_runtime.h>

#define NNODES 50000
#define NEDGES 200000
#define NSCANB ((NNODES + 255) / 256)   // 196 scan blocks

typedef short  bf16x8 __attribute__((ext_vector_type(8)));
typedef float  f32x4  __attribute__((ext_vector_type(4)));
typedef unsigned int u32x4 __attribute__((ext_vector_type(4)));

__device__ __forceinline__ unsigned short f2bf(float f) {
    union { float f; unsigned int u; } c; c.f = f;
    unsigned int r = c.u + 0x7fffu + ((c.u >> 16) & 1u);
    return (unsigned short)(r >> 16);
}
__device__ __forceinline__ float bflo(unsigned int v) {
    union { unsigned int u; float f; } c; c.u = v << 16;
    return c.f;
}
__device__ __forceinline__ float bfhi(unsigned int v) {
    union { unsigned int u; float f; } c; c.u = v & 0xffff0000u;
    return c.f;
}

// ---------------- fused prep + edge count (wide grid-stride) ----------------
// deg[] is zeroed by hipMemsetAsync before this launch.
#define PREP_B1 (256 * 1024)
#define PREP_B2 (64 * 512)
#define PREP_XC (NNODES * 64)
__global__ __launch_bounds__(256) void k_prepcount(const float* __restrict__ x,
                                                   const float* __restrict__ W1_rel,
                                                   const float* __restrict__ W1_root,
                                                   const float* __restrict__ W2_rel,
                                                   const float* __restrict__ W2_root,
                                                   const int* __restrict__ ei,
                                                   int* __restrict__ deg,
                                                   unsigned short* __restrict__ Bt1,
                                                   unsigned short* __restrict__ Bt2,
                                                   unsigned short* __restrict__ xb) {
    const int gtid = blockIdx.x * 256 + threadIdx.x;
    const int GS = gridDim.x * 256;
    for (int e = gtid; e < NEDGES; e += GS) atomicAdd(&deg[ei[NEDGES + e]], 1);
    for (int i = gtid; i < PREP_B1; i += GS) {
        int n = i >> 10, k = i & 1023;
        float v = (k < 512) ? W1_rel[k * 256 + n] : W1_root[(k - 512) * 256 + n];
        Bt1[i] = f2bf(v);
    }
    for (int i = gtid; i < PREP_B2; i += GS) {
        int n = i >> 9, k = i & 511;
        float v = (k < 256) ? W2_rel[k * 64 + n] : W2_root[(k - 256) * 64 + n];
        Bt2[i] = f2bf(v);
    }
    for (int i = gtid; i < PREP_XC; i += GS) {
        int n = i >> 6, c8 = (i & 63) * 8;
        const float* xp = x + (size_t)n * 512 + c8;
        float4 a = *(const float4*)xp;
        float4 bb = *(const float4*)(xp + 4);
        unsigned short o[8];
        o[0] = f2bf(a.x); o[1] = f2bf(a.y); o[2] = f2bf(a.z); o[3] = f2bf(a.w);
        o[4] = f2bf(bb.x); o[5] = f2bf(bb.y); o[6] = f2bf(bb.z); o[7] = f2bf(bb.w);
        *(u32x4*)(xb + (size_t)n * 512 + c8) = *(const u32x4*)o;
    }
}

// ---------------- CSR scan: block-local exclusive ----------------
__global__ __launch_bounds__(256) void k_scanA(const int* __restrict__ deg,
                                               int* __restrict__ rs,
                                               int* __restrict__ partials) {
    __shared__ int sm[256];
    int t = threadIdx.x, i = blockIdx.x * 256 + t;
    int v = (i < NNODES) ? deg[i] : 0;
    sm[t] = v;
    __syncthreads();
#pragma unroll
    for (int off = 1; off < 256; off <<= 1) {
        int u = (t >= off) ? sm[t - off] : 0;
        __syncthreads();
        sm[t] += u;
        __syncthreads();
    }
    if (i < NNODES) rs[i] = sm[t] - v;
    if (t == 255) partials[blockIdx.x] = sm[255];
}

// fused scanB+scanC: each block reduces partials[0..b-1] itself (196 ints)
__global__ __launch_bounds__(256) void k_scanC2(int* __restrict__ rs,
                                                const int* __restrict__ partials,
                                                int* __restrict__ cursor) {
    __shared__ int sm[256];
    int t = threadIdx.x, b = blockIdx.x;
    sm[t] = (t < b && t < NSCANB) ? partials[t] : 0;
    __syncthreads();
#pragma unroll
    for (int off = 128; off; off >>= 1) {
        if (t < off) sm[t] += sm[t + off];
        __syncthreads();
    }
    int off0 = sm[0];
    int i = b * 256 + t;
    if (i < NNODES) {
        int rv = rs[i] + off0;
        rs[i] = rv;
        cursor[i] = rv;
    }
    if (i == 0) rs[NNODES] = NEDGES;
}

__global__ void k_scatter(const int* __restrict__ ei, int* __restrict__ cursor,
                          int* __restrict__ srcs) {
    int e = blockIdx.x * 256 + threadIdx.x;
    if (e < NEDGES) {
        int d = ei[NEDGES + e];
        int p = atomicAdd(&cursor[d], 1);
        srcs[p] = ei[e];
    }
}

// ---------------- softmax aggregation (layer 1): wave-per-node -------------
__global__ __launch_bounds__(256) void k_agg1(const unsigned short* __restrict__ xb,
                                              const int* __restrict__ rs,
                                              const int* __restrict__ srcs,
                                              unsigned short* __restrict__ AggBuf) {
    int wv = threadIdx.x >> 6;
    int lane = threadIdx.x & 63;
    int n = blockIdx.x * 4 + wv;
    int e0 = rs[n], e1 = rs[n + 1];
    float nu[8], de[8];
#pragma unroll
    for (int j = 0; j < 8; ++j) { nu[j] = 0.f; de[j] = 0.f; }

    auto accum = [&](u32x4 r) {
#pragma unroll
        for (int p = 0; p < 4; ++p) {
            float v0 = bflo(r[p]), v1 = bfhi(r[p]);
            float E0 = __expf(v0), E1 = __expf(v1);
            de[2 * p] += E0; nu[2 * p] += E0 * v0;
            de[2 * p + 1] += E1; nu[2 * p + 1] += E1 * v1;
        }
    };

    int e = e0;
    for (; e + 3 < e1; e += 4) {
        int s0 = srcs[e], s1 = srcs[e + 1], s2 = srcs[e + 2], s3 = srcs[e + 3];
        u32x4 r0 = *(const u32x4*)(xb + (size_t)s0 * 512 + lane * 8);
        u32x4 r1 = *(const u32x4*)(xb + (size_t)s1 * 512 + lane * 8);
        u32x4 r2 = *(const u32x4*)(xb + (size_t)s2 * 512 + lane * 8);
        u32x4 r3 = *(const u32x4*)(xb + (size_t)s3 * 512 + lane * 8);
        accum(r0); accum(r1); accum(r2); accum(r3);
    }
    if (e + 1 < e1) {
        int s0 = srcs[e], s1 = srcs[e + 1];
        u32x4 r0 = *(const u32x4*)(xb + (size_t)s0 * 512 + lane * 8);
        u32x4 r1 = *(const u32x4*)(xb + (size_t)s1 * 512 + lane * 8);
        accum(r0); accum(r1);
        e += 2;
    }
    if (e < e1) {
        u32x4 r0 = *(const u32x4*)(xb + (size_t)srcs[e] * 512 + lane * 8);
        accum(r0);
    }
    unsigned short o[8];
#pragma unroll
    for (int j = 0; j < 8; ++j) o[j] = f2bf(nu[j] / fmaxf(de[j], 1e-16f));
    *(u32x4*)(AggBuf + (size_t)n * 512 + lane * 8) = *(const u32x4*)o;
}

// ---------------- sum aggregation (layer 2): wave-per-node ------------------
__global__ __launch_bounds__(256) void k_agg2(const int* __restrict__ rs,
                                              const int* __restrict__ srcs,
                                              const unsigned short* __restrict__ H1,
                                              unsigned short* __restrict__ Seg) {
    int wv = threadIdx.x >> 6;
    int lane = threadIdx.x & 63;
    int n = blockIdx.x * 4 + wv;
    int e0 = rs[n], e1 = rs[n + 1];
    float a[4] = {0.f, 0.f, 0.f, 0.f};

    auto accum = [&](uint2 r) {
        a[0] += bflo(r.x); a[1] += bfhi(r.x);
        a[2] += bflo(r.y); a[3] += bfhi(r.y);
    };

    int e = e0;
    for (; e + 3 < e1; e += 4) {
        int s0 = srcs[e], s1 = srcs[e + 1], s2 = srcs[e + 2], s3 = srcs[e + 3];
        uint2 r0 = *(const uint2*)(H1 + (size_t)s0 * 256 + lane * 4);
        uint2 r1 = *(const uint2*)(H1 + (size_t)s1 * 256 + lane * 4);
        uint2 r2 = *(const uint2*)(H1 + (size_t)s2 * 256 + lane * 4);
        uint2 r3 = *(const uint2*)(H1 + (size_t)s3 * 256 + lane * 4);
        accum(r0); accum(r1); accum(r2); accum(r3);
    }
    if (e + 1 < e1) {
        int s0 = srcs[e], s1 = srcs[e + 1];
        uint2 r0 = *(const uint2*)(H1 + (size_t)s0 * 256 + lane * 4);
        uint2 r1 = *(const uint2*)(H1 + (size_t)s1 * 256 + lane * 4);
        accum(r0); accum(r1);
        e += 2;
    }
    if (e < e1) {
        uint2 r0 = *(const uint2*)(H1 + (size_t)srcs[e] * 256 + lane * 4);
        accum(r0);
    }
    uint2 o;
    o.x = (unsigned int)f2bf(a[0]) | ((unsigned int)f2bf(a[1]) << 16);
    o.y = (unsigned int)f2bf(a[2]) | ((unsigned int)f2bf(a[3]) << 16);
    *(uint2*)(Seg + (size_t)n * 256 + lane * 4) = o;
}

// ---------------- GEMM1: 128x128 tile + counted-vmcnt double-buffer ---------
// Composition of the two validated levers: 128^2 tile (cost-free vs 64x128,
// R7) x 2-stage counted-vmcnt pipeline (R1's +6%). vmcnt(8) waits only the
// PRIOR buffer's 8 loads, issued one full 128-MFMA compute phase earlier.
__global__ __launch_bounds__(256) void k_gemm1(const unsigned short* __restrict__ A1,
                                               const unsigned short* __restrict__ A2,
                                               const unsigned short* __restrict__ Bt,
                                               const int* __restrict__ rs,
                                               const int* __restrict__ srcs,
                                               const float* __restrict__ r1,
                                               const float* __restrict__ r2,
                                               const float* __restrict__ bias,
                                               unsigned short* __restrict__ outp) {
    constexpr int BM = 128, BN = 128, BK = 64;
    __shared__ __align__(16) unsigned short As[2][BM * BK];   // 32 KB
    __shared__ __align__(16) unsigned short Bs[2][BN * BK];   // 32 KB
    __shared__ float s1t[BM];

    const int tid = threadIdx.x;
    const int w = tid >> 6;        // 0..3
    const int lane = tid & 63;
    const int lm = lane & 15;
    const int quad = lane >> 4;
    const int wr = w >> 1;         // 0..1
    const int wc = w & 1;          // 0..1
    const int rowbase = blockIdx.y * BM;
    const int colbase = blockIdx.x * BN;
    const int wrow = wr * 64;
    const int wcol = wc * 64;

    const int rsub = lane >> 3;
    const int csw = (lane & 7) ^ rsub;

    f32x4 acc[4][4];
#pragma unroll
    for (int mi = 0; mi < 4; ++mi)
#pragma unroll
        for (int ni = 0; ni < 4; ++ni) acc[mi][ni] = (f32x4){0.f, 0.f, 0.f, 0.f};

    // 8 global_load_lds per thread per stage (4 A + 4 B)
    auto stage = [&](unsigned short* Asb, unsigned short* Bsb, int kt) {
        const unsigned short* Ab = (kt < 512) ? A1 : A2;
        int kof = (kt < 512) ? kt : kt - 512;
#pragma unroll
        for (int l = 0; l < 4; ++l) {
            int r = w * 32 + l * 8;
            int gr = rowbase + r + rsub;
            if (gr >= NNODES) gr = NNODES - 1;
            const unsigned short* gp = Ab + (size_t)gr * 512 + kof + csw * 8;
            __builtin_amdgcn_global_load_lds(
                (const __attribute__((address_space(1))) void*)gp,
                (__attribute__((address_space(3))) void*)(Asb + r * BK), 16, 0, 0);
        }
#pragma unroll
        for (int l = 0; l < 4; ++l) {
            int r = w * 32 + l * 8;
            const unsigned short* gp = Bt + (size_t)(colbase + r + rsub) * 1024 + kt + csw * 8;
            __builtin_amdgcn_global_load_lds(
                (const __attribute__((address_space(1))) void*)gp,
                (__attribute__((address_space(3))) void*)(Bsb + r * BK), 16, 0, 0);
        }
    };

    auto compute = [&](const unsigned short* Asb, const unsigned short* Bsb) {
#pragma unroll
        for (int kk = 0; kk < BK; kk += 32) {
            const int kidx = (kk >> 3) + quad;
            const int phys = kidx ^ (lm & 7);
            bf16x8 af[4], bfr[4];
#pragma unroll
            for (int mi = 0; mi < 4; ++mi)
                af[mi] = __builtin_bit_cast(bf16x8,
                    *(const u32x4*)(Asb + (wrow + mi * 16 + lm) * BK + phys * 8));
#pragma unroll
            for (int ni = 0; ni < 4; ++ni)
                bfr[ni] = __builtin_bit_cast(bf16x8,
                    *(const u32x4*)(Bsb + (wcol + ni * 16 + lm) * BK + phys * 8));
#pragma unroll
            for (int mi = 0; mi < 4; ++mi)
#pragma unroll
                for (int ni = 0; ni < 4; ++ni)
                    acc[mi][ni] = __builtin_amdgcn_mfma_f32_16x16x32_bf16(
                        af[mi], bfr[ni], acc[mi][ni], 0, 0, 0);
        }
    };

    stage(As[0], Bs[0], 0);
#pragma unroll 1
    for (int t = 0; t < 16; t += 2) {
        // phase A: compute buf0 (staged last phase), prefetch buf1
        stage(As[1], Bs[1], (t + 1) * BK);
        asm volatile("s_waitcnt vmcnt(8)" ::: "memory");  // buf0's 8 loads done
        __builtin_amdgcn_s_barrier();
        __builtin_amdgcn_sched_barrier(0);
        compute(As[0], Bs[0]);
        __builtin_amdgcn_s_barrier();
        // phase B: compute buf1, prefetch buf0 (unless last tile)
        if (t + 2 < 16) {
            stage(As[0], Bs[0], (t + 2) * BK);
            asm volatile("s_waitcnt vmcnt(8)" ::: "memory");
        } else {
            asm volatile("s_waitcnt vmcnt(0)" ::: "memory");
        }
        __builtin_amdgcn_s_barrier();
        __builtin_amdgcn_sched_barrier(0);
        compute(As[1], Bs[1]);
        __builtin_amdgcn_s_barrier();
    }

    // per-row index softmax (threads 0..127, one row each)
    if (tid < BM) {
        int grow = rowbase + tid;
        float r_ = 0.f;
        if (grow < NNODES) {
            int e0 = rs[grow], e1 = rs[grow + 1];
            float m = -INFINITY, d = 0.f, q = 0.f;
            for (int e = e0; e < e1; ++e) {
                float v = (float)srcs[e];
                float nm = fmaxf(m, v);
                float sc = __expf(m - nm), ee = __expf(v - nm);
                d = d * sc + ee;
                q = q * sc + ee * v;
                m = nm;
            }
            r_ = q / fmaxf(d, 1e-16f);
        }
        s1t[tid] = r_;
    }
    __syncthreads();

#pragma unroll
    for (int ni = 0; ni < 4; ++ni) {
        int gc = colbase + wcol + ni * 16 + lm;
        float r1v = r1[gc], r2v = r2[gc], bv = bias[gc];
#pragma unroll
        for (int mi = 0; mi < 4; ++mi) {
#pragma unroll
            for (int r = 0; r < 4; ++r) {
                int lrow = wrow + mi * 16 + quad * 4 + r;
                int grow = rowbase + lrow;
                if (grow < NNODES) {
                    float v = acc[mi][ni][r] + s1t[lrow] * r1v + (float)grow * r2v + bv;
                    v = (v >= 0.f) ? v : 0.01f * v;
                    outp[(size_t)grow * 256 + gc] = f2bf(v);
                }
            }
        }
    }
}

// ---------------- GEMM2 + fused head: 64x64 tile, split-A [Seg|H1] ----------
// R0/R4 single-buffered form (known-good).
__global__ __launch_bounds__(256) void k_gemm2h(const unsigned short* __restrict__ A1,
                                                const unsigned short* __restrict__ A2,
                                                const unsigned short* __restrict__ Bt,
                                                const int* __restrict__ rs,
                                                const int* __restrict__ srcs,
                                                const float* __restrict__ r1,
                                                const float* __restrict__ r2,
                                                const float* __restrict__ bias,
                                                const float* __restrict__ Wp,
                                                const float* __restrict__ bp,
                                                const float* __restrict__ Wr,
                                                const float* __restrict__ br,
                                                float* __restrict__ out) {
    constexpr int BM = 64, BN = 64, BK = 64;
    __shared__ __align__(16) unsigned short As[BM * BK];
    __shared__ __align__(16) unsigned short Bs[BN * BK];
    __shared__ float h2t[BM * 65];
    __shared__ float s1t[BM];

    const int tid = threadIdx.x;
    const int w = tid >> 6;
    const int lane = tid & 63;
    const int lm = lane & 15;
    const int quad = lane >> 4;
    const int rowbase = blockIdx.x * BM;
    const int wrow = w * 16;

    const int rsub = lane >> 3;
    const int csw = (lane & 7) ^ rsub;

    f32x4 acc[4];
#pragma unroll
    for (int ni = 0; ni < 4; ++ni) acc[ni] = (f32x4){0.f, 0.f, 0.f, 0.f};

    for (int kt = 0; kt < 512; kt += BK) {
        const unsigned short* Ab = (kt < 256) ? A1 : A2;
        int kof = (kt < 256) ? kt : kt - 256;
#pragma unroll
        for (int l = 0; l < 2; ++l) {
            int r = w * 16 + l * 8;
            int gr = rowbase + r + rsub;
            if (gr >= NNODES) gr = NNODES - 1;
            const unsigned short* gp = Ab + (size_t)gr * 256 + kof + csw * 8;
            __builtin_amdgcn_global_load_lds(
                (const __attribute__((address_space(1))) void*)gp,
                (__attribute__((address_space(3))) void*)(As + r * BK), 16, 0, 0);
        }
#pragma unroll
        for (int l = 0; l < 2; ++l) {
            int r = w * 16 + l * 8;
            const unsigned short* gp = Bt + (size_t)(r + rsub) * 512 + kt + csw * 8;
            __builtin_amdgcn_global_load_lds(
                (const __attribute__((address_space(1))) void*)gp,
                (__attribute__((address_space(3))) void*)(Bs + r * BK), 16, 0, 0);
        }
        __syncthreads();
#pragma unroll
        for (int kk = 0; kk < BK; kk += 32) {
            const int kidx = (kk >> 3) + quad;
            const int phys = kidx ^ (lm & 7);
            bf16x8 af;
            af = __builtin_bit_cast(bf16x8,
                *(const u32x4*)(As + (wrow + lm) * BK + phys * 8));
            bf16x8 bfr[4];
#pragma unroll
            for (int ni = 0; ni < 4; ++ni)
                bfr[ni] = __builtin_bit_cast(bf16x8,
                    *(const u32x4*)(Bs + (ni * 16 + lm) * BK + phys * 8));
#pragma unroll
            for (int ni = 0; ni < 4; ++ni)
                acc[ni] = __builtin_amdgcn_mfma_f32_16x16x32_bf16(
                    af, bfr[ni], acc[ni], 0, 0, 0);
        }
        __syncthreads();
    }

    // per-row index sum
    if (tid < BM) {
        int grow = rowbase + tid;
        float si = 0.f;
        if (grow < NNODES) {
            int e0 = rs[grow], e1 = rs[grow + 1];
            for (int e = e0; e < e1; ++e) si += (float)srcs[e];
        }
        s1t[tid] = si;
    }
    __syncthreads();

    // epilogue -> LDS h2 tile
#pragma unroll
    for (int ni = 0; ni < 4; ++ni) {
        int gc = ni * 16 + lm;
        float r1v = r1[gc], r2v = r2[gc], bv = bias[gc];
#pragma unroll
        for (int r = 0; r < 4; ++r) {
            int lrow = wrow + quad * 4 + r;
            int grow = rowbase + lrow;
            float v = acc[ni][r] + s1t[lrow] * r1v + (float)grow * r2v + bv;
            v = (v >= 0.f) ? v : 0.01f * v;
            h2t[lrow * 65 + gc] = v;
        }
    }
    __syncthreads();

    // head: threads 0..63, one row each
    if (tid < BM) {
        int grow = rowbase + tid;
        if (grow < NNODES) {
            const float* hv = h2t + tid * 65;
            float idx = (float)grow;
            float p0 = 0.f, p1 = 0.f, p2 = 0.f;
            float r0 = 0.f, r1a = 0.f, r2a = 0.f, r3 = 0.f;
#pragma unroll 8
            for (int c = 0; c < 64; ++c) {
                float v = hv[c];
                p0 += v * Wp[c * 3 + 0];
                p1 += v * Wp[c * 3 + 1];
                p2 += v * Wp[c * 3 + 2];
                r0 += v * Wr[c * 4 + 0];
                r1a += v * Wr[c * 4 + 1];
                r2a += v * Wr[c * 4 + 2];
                r3 += v * Wr[c * 4 + 3];
            }
            p0 += idx * Wp[64 * 3 + 0] + bp[0];
            p1 += idx * Wp[64 * 3 + 1] + bp[1];
            p2 += idx * Wp[64 * 3 + 2] + bp[2];
            r0 += idx * Wr[64 * 4 + 0] + br[0];
            r1a += idx * Wr[64 * 4 + 1] + br[1];
            r2a += idx * Wr[64 * 4 + 2] + br[2];
            r3 += idx * Wr[64 * 4 + 3] + br[3];
            float nrm = fmaxf(sqrtf(r0 * r0 + r1a * r1a + r2a * r2a + r3 * r3), 1e-12f);
            float* op = out + (size_t)grow * 7;
            op[0] = p0; op[1] = p1; op[2] = p2;
            op[3] = r0 / nrm; op[4] = r1a / nrm; op[5] = r2a / nrm; op[6] = r3 / nrm;
        }
    }
}

extern "C" void kernel_launch(void* const* d_in, const int* in_sizes, int n_in,
                              void* d_out, int out_size, void* d_ws, size_t ws_size,
                              hipStream_t stream) {
    const float* x       = (const float*)d_in[0];
    const float* W1_rel  = (const float*)d_in[1];
    const float* b1      = (const float*)d_in[2];
    const float* W1_root = (const float*)d_in[3];
    const float* W2_rel  = (const float*)d_in[4];
    const float* b2      = (const float*)d_in[5];
    const float* W2_root = (const float*)d_in[6];
    const float* Wp      = (const float*)d_in[7];
    const float* bp      = (const float*)d_in[8];
    const float* Wr      = (const float*)d_in[9];
    const float* br      = (const float*)d_in[10];
    const int*   ei      = (const int*)d_in[11];
    float* out = (float*)d_out;

    char* ws = (char*)d_ws;
    size_t off = 0;
    auto alloc = [&](size_t bytes) {
        size_t o = off;
        off = (off + bytes + 255) & ~(size_t)255;
        return (void*)(ws + o);
    };
    int*   deg       = (int*)alloc(NNODES * 4);
    int*   cursor    = (int*)alloc(NNODES * 4);
    int*   row_start = (int*)alloc((NNODES + 1) * 4);
    int*   srcs      = (int*)alloc(NEDGES * 4);
    int*   partials  = (int*)alloc(NSCANB * 4);
    unsigned short* xb     = (unsigned short*)alloc((size_t)NNODES * 512 * 2);
    unsigned short* AggBuf = (unsigned short*)alloc((size_t)NNODES * 512 * 2);
    unsigned short* H1     = (unsigned short*)alloc((size_t)NNODES * 256 * 2);
    unsigned short* Seg    = (unsigned short*)alloc((size_t)NNODES * 256 * 2);
    unsigned short* Bt1    = (unsigned short*)alloc(256 * 1024 * 2);
    unsigned short* Bt2    = (unsigned short*)alloc(64 * 512 * 2);

    hipMemsetAsync(deg, 0, NNODES * 4, stream);

    k_prepcount<<<2048, 256, 0, stream>>>(
        x, W1_rel, W1_root, W2_rel, W2_root, ei, deg, Bt1, Bt2, xb);

    k_scanA<<<NSCANB, 256, 0, stream>>>(deg, row_start, partials);
    k_scanC2<<<NSCANB, 256, 0, stream>>>(row_start, partials, cursor);
    k_scatter<<<(NEDGES + 255) / 256, 256, 0, stream>>>(ei, cursor, srcs);

    k_agg1<<<NNODES / 4, 256, 0, stream>>>(xb, row_start, srcs, AggBuf);

    // GEMM1: [AggBuf | xb] @ Bt1^T -> H1 (bf16, stride 256). grid (col, row)
    k_gemm1<<<dim3(2, (NNODES + 127) / 128), 256, 0, stream>>>(
        AggBuf, xb, Bt1, row_start, srcs, W1_rel + 512 * 256, W1_root + 512 * 256, b1, H1);

    k_agg2<<<NNODES / 4, 256, 0, stream>>>(row_start, srcs, H1, Seg);

    // GEMM2 + head: [Seg | H1] @ Bt2^T -> out
    k_gemm2h<<<(NNODES + 63) / 64, 256, 0, stream>>>(
        Seg, H1, Bt2, row_start, srcs, W2_rel + 256 * 64, W2_root + 256 * 64, b2,
        Wp, bp, Wr, br, out);
}

// Round 10
// 335.758 us; speedup vs baseline: 1.3251x; 1.0045x over previous
//
#include <hip/hip_runtime.h>

#define NNODES 50000
#define NEDGES 200000
#define NSCANB ((NNODES + 255) / 256)   // 196 scan blocks

typedef short  bf16x8 __attribute__((ext_vector_type(8)));
typedef float  f32x4  __attribute__((ext_vector_type(4)));
typedef unsigned int u32x4 __attribute__((ext_vector_type(4)));

__device__ __forceinline__ unsigned short f2bf(float f) {
    union { float f; unsigned int u; } c; c.f = f;
    unsigned int r = c.u + 0x7fffu + ((c.u >> 16) & 1u);
    return (unsigned short)(r >> 16);
}
__device__ __forceinline__ float bf2f(unsigned short h) {
    union { unsigned int u; float f; } c; c.u = ((unsigned int)h) << 16;
    return c.f;
}
__device__ __forceinline__ float bflo(unsigned int v) {
    union { unsigned int u; float f; } c; c.u = v << 16;
    return c.f;
}
__device__ __forceinline__ float bfhi(unsigned int v) {
    union { unsigned int u; float f; } c; c.u = v & 0xffff0000u;
    return c.f;
}

// ---------------- fused prep + edge count (wide grid-stride) ----------------
// deg[] is zeroed by hipMemsetAsync before this launch.
// Bt2n layout [128][256]: rows 0..63 = W2_rel columns, rows 64..127 = W2_root
// columns (both restricted to k<256; the index rows are applied in k_agg2h).
#define PREP_B1 (256 * 1024)
#define PREP_B2 (128 * 256)
#define PREP_XC (NNODES * 64)
__global__ __launch_bounds__(256) void k_prepcount(const float* __restrict__ x,
                                                   const float* __restrict__ W1_rel,
                                                   const float* __restrict__ W1_root,
                                                   const float* __restrict__ W2_rel,
                                                   const float* __restrict__ W2_root,
                                                   const int* __restrict__ ei,
                                                   int* __restrict__ deg,
                                                   unsigned short* __restrict__ Bt1,
                                                   unsigned short* __restrict__ Bt2,
                                                   unsigned short* __restrict__ xb) {
    const int gtid = blockIdx.x * 256 + threadIdx.x;
    const int GS = gridDim.x * 256;
    for (int e = gtid; e < NEDGES; e += GS) atomicAdd(&deg[ei[NEDGES + e]], 1);
    for (int i = gtid; i < PREP_B1; i += GS) {
        int n = i >> 10, k = i & 1023;
        float v = (k < 512) ? W1_rel[k * 256 + n] : W1_root[(k - 512) * 256 + n];
        Bt1[i] = f2bf(v);
    }
    for (int i = gtid; i < PREP_B2; i += GS) {
        int n = i >> 8, k = i & 255;
        float v = (n < 64) ? W2_rel[k * 64 + n] : W2_root[k * 64 + (n - 64)];
        Bt2[i] = f2bf(v);
    }
    for (int i = gtid; i < PREP_XC; i += GS) {
        int n = i >> 6, c8 = (i & 63) * 8;
        const float* xp = x + (size_t)n * 512 + c8;
        float4 a = *(const float4*)xp;
        float4 bb = *(const float4*)(xp + 4);
        unsigned short o[8];
        o[0] = f2bf(a.x); o[1] = f2bf(a.y); o[2] = f2bf(a.z); o[3] = f2bf(a.w);
        o[4] = f2bf(bb.x); o[5] = f2bf(bb.y); o[6] = f2bf(bb.z); o[7] = f2bf(bb.w);
        *(u32x4*)(xb + (size_t)n * 512 + c8) = *(const u32x4*)o;
    }
}

// ---------------- CSR scan: block-local exclusive ----------------
__global__ __launch_bounds__(256) void k_scanA(const int* __restrict__ deg,
                                               int* __restrict__ rs,
                                               int* __restrict__ partials) {
    __shared__ int sm[256];
    int t = threadIdx.x, i = blockIdx.x * 256 + t;
    int v = (i < NNODES) ? deg[i] : 0;
    sm[t] = v;
    __syncthreads();
#pragma unroll
    for (int off = 1; off < 256; off <<= 1) {
        int u = (t >= off) ? sm[t - off] : 0;
        __syncthreads();
        sm[t] += u;
        __syncthreads();
    }
    if (i < NNODES) rs[i] = sm[t] - v;
    if (t == 255) partials[blockIdx.x] = sm[255];
}

// fused scanB+scanC: each block reduces partials[0..b-1] itself (196 ints)
__global__ __launch_bounds__(256) void k_scanC2(int* __restrict__ rs,
                                                const int* __restrict__ partials,
                                                int* __restrict__ cursor) {
    __shared__ int sm[256];
    int t = threadIdx.x, b = blockIdx.x;
    sm[t] = (t < b && t < NSCANB) ? partials[t] : 0;
    __syncthreads();
#pragma unroll
    for (int off = 128; off; off >>= 1) {
        if (t < off) sm[t] += sm[t + off];
        __syncthreads();
    }
    int off0 = sm[0];
    int i = b * 256 + t;
    if (i < NNODES) {
        int rv = rs[i] + off0;
        rs[i] = rv;
        cursor[i] = rv;
    }
    if (i == 0) rs[NNODES] = NEDGES;
}

__global__ void k_scatter(const int* __restrict__ ei, int* __restrict__ cursor,
                          int* __restrict__ srcs) {
    int e = blockIdx.x * 256 + threadIdx.x;
    if (e < NEDGES) {
        int d = ei[NEDGES + e];
        int p = atomicAdd(&cursor[d], 1);
        srcs[p] = ei[e];
    }
}

// ---------------- softmax aggregation (layer 1): wave-per-node -------------
__global__ __launch_bounds__(256) void k_agg1(const unsigned short* __restrict__ xb,
                                              const int* __restrict__ rs,
                                              const int* __restrict__ srcs,
                                              unsigned short* __restrict__ AggBuf) {
    int wv = threadIdx.x >> 6;
    int lane = threadIdx.x & 63;
    int n = blockIdx.x * 4 + wv;
    int e0 = rs[n], e1 = rs[n + 1];
    float nu[8], de[8];
#pragma unroll
    for (int j = 0; j < 8; ++j) { nu[j] = 0.f; de[j] = 0.f; }

    auto accum = [&](u32x4 r) {
#pragma unroll
        for (int p = 0; p < 4; ++p) {
            float v0 = bflo(r[p]), v1 = bfhi(r[p]);
            float E0 = __expf(v0), E1 = __expf(v1);
            de[2 * p] += E0; nu[2 * p] += E0 * v0;
            de[2 * p + 1] += E1; nu[2 * p + 1] += E1 * v1;
        }
    };

    int e = e0;
    for (; e + 3 < e1; e += 4) {
        int s0 = srcs[e], s1 = srcs[e + 1], s2 = srcs[e + 2], s3 = srcs[e + 3];
        u32x4 r0 = *(const u32x4*)(xb + (size_t)s0 * 512 + lane * 8);
        u32x4 r1 = *(const u32x4*)(xb + (size_t)s1 * 512 + lane * 8);
        u32x4 r2 = *(const u32x4*)(xb + (size_t)s2 * 512 + lane * 8);
        u32x4 r3 = *(const u32x4*)(xb + (size_t)s3 * 512 + lane * 8);
        accum(r0); accum(r1); accum(r2); accum(r3);
    }
    if (e + 1 < e1) {
        int s0 = srcs[e], s1 = srcs[e + 1];
        u32x4 r0 = *(const u32x4*)(xb + (size_t)s0 * 512 + lane * 8);
        u32x4 r1 = *(const u32x4*)(xb + (size_t)s1 * 512 + lane * 8);
        accum(r0); accum(r1);
        e += 2;
    }
    if (e < e1) {
        u32x4 r0 = *(const u32x4*)(xb + (size_t)srcs[e] * 512 + lane * 8);
        accum(r0);
    }
    unsigned short o[8];
#pragma unroll
    for (int j = 0; j < 8; ++j) o[j] = f2bf(nu[j] / fmaxf(de[j], 1e-16f));
    *(u32x4*)(AggBuf + (size_t)n * 512 + lane * 8) = *(const u32x4*)o;
}

// ---------------- GEMM1: 64x128 tile, split-A, counted-vmcnt dbuf -----------
// Measured-best gemm1 structure (R1/R4: 67.0-67.3 us).
__global__ __launch_bounds__(256) void k_gemm1(const unsigned short* __restrict__ A1,
                                               const unsigned short* __restrict__ A2,
                                               const unsigned short* __restrict__ Bt,
                                               const int* __restrict__ rs,
                                               const int* __restrict__ srcs,
                                               const float* __restrict__ r1,
                                               const float* __restrict__ r2,
                                               const float* __restrict__ bias,
                                               unsigned short* __restrict__ outp) {
    constexpr int BM = 64, BN = 128, BK = 64;
    __shared__ __align__(16) unsigned short As[2][BM * BK];
    __shared__ __align__(16) unsigned short Bs[2][BN * BK];
    __shared__ float s1t[BM];

    const int tid = threadIdx.x;
    const int w = tid >> 6;
    const int lane = tid & 63;
    const int lm = lane & 15;
    const int quad = lane >> 4;
    const int wr = w >> 1;
    const int wc = w & 1;
    const int rowbase = blockIdx.y * BM;
    const int colbase = blockIdx.x * BN;
    const int wrow = wr * 32;
    const int wcol = wc * 64;

    const int rsub = lane >> 3;
    const int csw = (lane & 7) ^ rsub;

    f32x4 acc[2][4];
#pragma unroll
    for (int mi = 0; mi < 2; ++mi)
#pragma unroll
        for (int ni = 0; ni < 4; ++ni) acc[mi][ni] = (f32x4){0.f, 0.f, 0.f, 0.f};

    // 6 global_load_lds per thread per stage (2 A + 4 B)
    auto stage = [&](unsigned short* Asb, unsigned short* Bsb, int kt) {
        const unsigned short* Ab = (kt < 512) ? A1 : A2;
        int kof = (kt < 512) ? kt : kt - 512;
#pragma unroll
        for (int l = 0; l < 2; ++l) {
            int r = w * 16 + l * 8;
            int gr = rowbase + r + rsub;
            if (gr >= NNODES) gr = NNODES - 1;
            const unsigned short* gp = Ab + (size_t)gr * 512 + kof + csw * 8;
            __builtin_amdgcn_global_load_lds(
                (const __attribute__((address_space(1))) void*)gp,
                (__attribute__((address_space(3))) void*)(Asb + r * BK), 16, 0, 0);
        }
#pragma unroll
        for (int l = 0; l < 4; ++l) {
            int r = w * 32 + l * 8;
            const unsigned short* gp = Bt + (size_t)(colbase + r + rsub) * 1024 + kt + csw * 8;
            __builtin_amdgcn_global_load_lds(
                (const __attribute__((address_space(1))) void*)gp,
                (__attribute__((address_space(3))) void*)(Bsb + r * BK), 16, 0, 0);
        }
    };

    auto compute = [&](const unsigned short* Asb, const unsigned short* Bsb) {
#pragma unroll
        for (int kk = 0; kk < BK; kk += 32) {
            const int kidx = (kk >> 3) + quad;
            const int phys = kidx ^ (lm & 7);
            bf16x8 af[2], bfr[4];
#pragma unroll
            for (int mi = 0; mi < 2; ++mi)
                af[mi] = __builtin_bit_cast(bf16x8,
                    *(const u32x4*)(Asb + (wrow + mi * 16 + lm) * BK + phys * 8));
#pragma unroll
            for (int ni = 0; ni < 4; ++ni)
                bfr[ni] = __builtin_bit_cast(bf16x8,
                    *(const u32x4*)(Bsb + (wcol + ni * 16 + lm) * BK + phys * 8));
#pragma unroll
            for (int mi = 0; mi < 2; ++mi)
#pragma unroll
                for (int ni = 0; ni < 4; ++ni)
                    acc[mi][ni] = __builtin_amdgcn_mfma_f32_16x16x32_bf16(
                        af[mi], bfr[ni], acc[mi][ni], 0, 0, 0);
        }
    };

    stage(As[0], Bs[0], 0);
#pragma unroll 1
    for (int t = 0; t < 16; t += 2) {
        stage(As[1], Bs[1], (t + 1) * BK);
        asm volatile("s_waitcnt vmcnt(6)" ::: "memory");
        __builtin_amdgcn_s_barrier();
        __builtin_amdgcn_sched_barrier(0);
        compute(As[0], Bs[0]);
        __builtin_amdgcn_s_barrier();
        if (t + 2 < 16) {
            stage(As[0], Bs[0], (t + 2) * BK);
            asm volatile("s_waitcnt vmcnt(6)" ::: "memory");
        } else {
            asm volatile("s_waitcnt vmcnt(0)" ::: "memory");
        }
        __builtin_amdgcn_s_barrier();
        __builtin_amdgcn_sched_barrier(0);
        compute(As[1], Bs[1]);
        __builtin_amdgcn_s_barrier();
    }

    // per-row index softmax (max-shifted: values up to 5e4)
    if (tid < BM) {
        int grow = rowbase + tid;
        float r_ = 0.f;
        if (grow < NNODES) {
            int e0 = rs[grow], e1 = rs[grow + 1];
            float m = -INFINITY, d = 0.f, q = 0.f;
            for (int e = e0; e < e1; ++e) {
                float v = (float)srcs[e];
                float nm = fmaxf(m, v);
                float sc = __expf(m - nm), ee = __expf(v - nm);
                d = d * sc + ee;
                q = q * sc + ee * v;
                m = nm;
            }
            r_ = q / fmaxf(d, 1e-16f);
        }
        s1t[tid] = r_;
    }
    __syncthreads();

#pragma unroll
    for (int ni = 0; ni < 4; ++ni) {
        int gc = colbase + wcol + ni * 16 + lm;
        float r1v = r1[gc], r2v = r2[gc], bv = bias[gc];
#pragma unroll
        for (int mi = 0; mi < 2; ++mi) {
#pragma unroll
            for (int r = 0; r < 4; ++r) {
                int lrow = wrow + mi * 16 + quad * 4 + r;
                int grow = rowbase + lrow;
                if (grow < NNODES) {
                    float v = acc[mi][ni][r] + s1t[lrow] * r1v + (float)grow * r2v + bv;
                    v = (v >= 0.f) ? v : 0.01f * v;
                    outp[(size_t)grow * 256 + gc] = f2bf(v);
                }
            }
        }
    }
}

// ---------------- GEMM2 (restructured): GR = H1 @ [W2_rel | W2_root] --------
// Sum-aggregation is LINEAR -> commutes with the matmul. Compute the K=256
// GEMM first (half the A-traffic of the old K=512 split-A form, no Seg
// buffer), aggregate the 64-wide G rows afterwards in k_agg2h.
// Output GR [N][128] bf16: cols 0..63 = G = H1@W2_rel, 64..127 = R = H1@W2_root.
__global__ __launch_bounds__(256) void k_gemm2(const unsigned short* __restrict__ H1,
                                               const unsigned short* __restrict__ Bt,
                                               unsigned short* __restrict__ GR) {
    constexpr int BM = 64, BN = 128, BK = 64;
    __shared__ __align__(16) unsigned short As[BM * BK];   // 8 KB
    __shared__ __align__(16) unsigned short Bs[BN * BK];   // 16 KB

    const int tid = threadIdx.x;
    const int w = tid >> 6;
    const int lane = tid & 63;
    const int lm = lane & 15;
    const int quad = lane >> 4;
    const int wr = w >> 1;
    const int wc = w & 1;
    const int rowbase = blockIdx.x * BM;
    const int wrow = wr * 32;
    const int wcol = wc * 64;

    const int rsub = lane >> 3;
    const int csw = (lane & 7) ^ rsub;

    f32x4 acc[2][4];
#pragma unroll
    for (int mi = 0; mi < 2; ++mi)
#pragma unroll
        for (int ni = 0; ni < 4; ++ni) acc[mi][ni] = (f32x4){0.f, 0.f, 0.f, 0.f};

#pragma unroll 1
    for (int kt = 0; kt < 256; kt += BK) {
        // stage A (64x64): 2 loads/thread
#pragma unroll
        for (int l = 0; l < 2; ++l) {
            int r = w * 16 + l * 8;
            int gr = rowbase + r + rsub;
            if (gr >= NNODES) gr = NNODES - 1;
            const unsigned short* gp = H1 + (size_t)gr * 256 + kt + csw * 8;
            __builtin_amdgcn_global_load_lds(
                (const __attribute__((address_space(1))) void*)gp,
                (__attribute__((address_space(3))) void*)(As + r * BK), 16, 0, 0);
        }
        // stage B (128x64): 4 loads/thread
#pragma unroll
        for (int l = 0; l < 4; ++l) {
            int r = w * 32 + l * 8;
            const unsigned short* gp = Bt + (size_t)(r + rsub) * 256 + kt + csw * 8;
            __builtin_amdgcn_global_load_lds(
                (const __attribute__((address_space(1))) void*)gp,
                (__attribute__((address_space(3))) void*)(Bs + r * BK), 16, 0, 0);
        }
        __syncthreads();
#pragma unroll
        for (int kk = 0; kk < BK; kk += 32) {
            const int kidx = (kk >> 3) + quad;
            const int phys = kidx ^ (lm & 7);
            bf16x8 af[2], bfr[4];
#pragma unroll
            for (int mi = 0; mi < 2; ++mi)
                af[mi] = __builtin_bit_cast(bf16x8,
                    *(const u32x4*)(As + (wrow + mi * 16 + lm) * BK + phys * 8));
#pragma unroll
            for (int ni = 0; ni < 4; ++ni)
                bfr[ni] = __builtin_bit_cast(bf16x8,
                    *(const u32x4*)(Bs + (wcol + ni * 16 + lm) * BK + phys * 8));
#pragma unroll
            for (int mi = 0; mi < 2; ++mi)
#pragma unroll
                for (int ni = 0; ni < 4; ++ni)
                    acc[mi][ni] = __builtin_amdgcn_mfma_f32_16x16x32_bf16(
                        af[mi], bfr[ni], acc[mi][ni], 0, 0, 0);
        }
        __syncthreads();
    }

    // raw epilogue: no bias / activation (applied in k_agg2h)
#pragma unroll
    for (int ni = 0; ni < 4; ++ni) {
        int gc = wcol + ni * 16 + lm;
#pragma unroll
        for (int mi = 0; mi < 2; ++mi) {
#pragma unroll
            for (int r = 0; r < 4; ++r) {
                int lrow = wrow + mi * 16 + quad * 4 + r;
                int grow = rowbase + lrow;
                if (grow < NNODES)
                    GR[(size_t)grow * 128 + gc] = f2bf(acc[mi][ni][r]);
            }
        }
    }
}

// ---------------- agg2 + head (fused, wave-per-node) ------------------------
// h2 = sum_{src} G[src] + si*r1 + R[n] + n*r2 + b2, leaky-relu, then the
// 7-output head via butterfly reductions. Gathers 128 B/edge (4x less than
// the old Seg path).
__global__ __launch_bounds__(256) void k_agg2h(const int* __restrict__ rs,
                                               const int* __restrict__ srcs,
                                               const unsigned short* __restrict__ GR,
                                               const float* __restrict__ r1,
                                               const float* __restrict__ r2,
                                               const float* __restrict__ bias,
                                               const float* __restrict__ Wp,
                                               const float* __restrict__ bp,
                                               const float* __restrict__ Wr,
                                               const float* __restrict__ br,
                                               float* __restrict__ out) {
    const int wv = threadIdx.x >> 6;
    const int lane = threadIdx.x & 63;
    const int n = blockIdx.x * 4 + wv;
    const int e0 = rs[n], e1 = rs[n + 1];

    float g = 0.f, si = 0.f;
    int e = e0;
    for (; e + 3 < e1; e += 4) {
        int s0 = srcs[e], s1 = srcs[e + 1], s2 = srcs[e + 2], s3 = srcs[e + 3];
        float g0 = bf2f(GR[(size_t)s0 * 128 + lane]);
        float g1 = bf2f(GR[(size_t)s1 * 128 + lane]);
        float g2 = bf2f(GR[(size_t)s2 * 128 + lane]);
        float g3 = bf2f(GR[(size_t)s3 * 128 + lane]);
        g += (g0 + g1) + (g2 + g3);
        si += (float)(s0 + s1) + (float)(s2 + s3);
    }
    if (e + 1 < e1) {
        int s0 = srcs[e], s1 = srcs[e + 1];
        g += bf2f(GR[(size_t)s0 * 128 + lane]) + bf2f(GR[(size_t)s1 * 128 + lane]);
        si += (float)(s0 + s1);
        e += 2;
    }
    if (e < e1) {
        int s0 = srcs[e];
        g += bf2f(GR[(size_t)s0 * 128 + lane]);
        si += (float)s0;
    }

    float h2 = g + si * r1[lane] + bf2f(GR[(size_t)n * 128 + 64 + lane])
             + (float)n * r2[lane] + bias[lane];
    h2 = (h2 >= 0.f) ? h2 : 0.01f * h2;

    // head partial products (lane = feature index)
    float p0 = h2 * Wp[lane * 3 + 0];
    float p1 = h2 * Wp[lane * 3 + 1];
    float p2 = h2 * Wp[lane * 3 + 2];
    float q0 = h2 * Wr[lane * 4 + 0];
    float q1 = h2 * Wr[lane * 4 + 1];
    float q2 = h2 * Wr[lane * 4 + 2];
    float q3 = h2 * Wr[lane * 4 + 3];
#pragma unroll
    for (int m = 1; m < 64; m <<= 1) {
        p0 += __shfl_xor(p0, m);
        p1 += __shfl_xor(p1, m);
        p2 += __shfl_xor(p2, m);
        q0 += __shfl_xor(q0, m);
        q1 += __shfl_xor(q1, m);
        q2 += __shfl_xor(q2, m);
        q3 += __shfl_xor(q3, m);
    }
    const float idx = (float)n;
    p0 += idx * Wp[64 * 3 + 0] + bp[0];
    p1 += idx * Wp[64 * 3 + 1] + bp[1];
    p2 += idx * Wp[64 * 3 + 2] + bp[2];
    q0 += idx * Wr[64 * 4 + 0] + br[0];
    q1 += idx * Wr[64 * 4 + 1] + br[1];
    q2 += idx * Wr[64 * 4 + 2] + br[2];
    q3 += idx * Wr[64 * 4 + 3] + br[3];
    float nrm = fmaxf(sqrtf(q0 * q0 + q1 * q1 + q2 * q2 + q3 * q3), 1e-12f);
    float o = (lane == 0) ? p0 : (lane == 1) ? p1 : (lane == 2) ? p2
            : (lane == 3) ? q0 / nrm : (lane == 4) ? q1 / nrm
            : (lane == 5) ? q2 / nrm : q3 / nrm;
    if (lane < 7) out[(size_t)n * 7 + lane] = o;
}

extern "C" void kernel_launch(void* const* d_in, const int* in_sizes, int n_in,
                              void* d_out, int out_size, void* d_ws, size_t ws_size,
                              hipStream_t stream) {
    const float* x       = (const float*)d_in[0];
    const float* W1_rel  = (const float*)d_in[1];
    const float* b1      = (const float*)d_in[2];
    const float* W1_root = (const float*)d_in[3];
    const float* W2_rel  = (const float*)d_in[4];
    const float* b2      = (const float*)d_in[5];
    const float* W2_root = (const float*)d_in[6];
    const float* Wp      = (const float*)d_in[7];
    const float* bp      = (const float*)d_in[8];
    const float* Wr      = (const float*)d_in[9];
    const float* br      = (const float*)d_in[10];
    const int*   ei      = (const int*)d_in[11];
    float* out = (float*)d_out;

    char* ws = (char*)d_ws;
    size_t off = 0;
    auto alloc = [&](size_t bytes) {
        size_t o = off;
        off = (off + bytes + 255) & ~(size_t)255;
        return (void*)(ws + o);
    };
    int*   deg       = (int*)alloc(NNODES * 4);
    int*   cursor    = (int*)alloc(NNODES * 4);
    int*   row_start = (int*)alloc((NNODES + 1) * 4);
    int*   srcs      = (int*)alloc(NEDGES * 4);
    int*   partials  = (int*)alloc(NSCANB * 4);
    unsigned short* xb     = (unsigned short*)alloc((size_t)NNODES * 512 * 2);
    unsigned short* AggBuf = (unsigned short*)alloc((size_t)NNODES * 512 * 2);
    unsigned short* H1     = (unsigned short*)alloc((size_t)NNODES * 256 * 2);
    unsigned short* GR     = (unsigned short*)alloc((size_t)NNODES * 128 * 2);
    unsigned short* Bt1    = (unsigned short*)alloc(256 * 1024 * 2);
    unsigned short* Bt2    = (unsigned short*)alloc(128 * 256 * 2);

    hipMemsetAsync(deg, 0, NNODES * 4, stream);

    k_prepcount<<<2048, 256, 0, stream>>>(
        x, W1_rel, W1_root, W2_rel, W2_root, ei, deg, Bt1, Bt2, xb);

    k_scanA<<<NSCANB, 256, 0, stream>>>(deg, row_start, partials);
    k_scanC2<<<NSCANB, 256, 0, stream>>>(row_start, partials, cursor);
    k_scatter<<<(NEDGES + 255) / 256, 256, 0, stream>>>(ei, cursor, srcs);

    k_agg1<<<NNODES / 4, 256, 0, stream>>>(xb, row_start, srcs, AggBuf);

    // GEMM1: [AggBuf | xb] @ Bt1^T -> H1 (bf16, stride 256). grid (col, row)
    k_gemm1<<<dim3(2, (NNODES + 63) / 64), 256, 0, stream>>>(
        AggBuf, xb, Bt1, row_start, srcs, W1_rel + 512 * 256, W1_root + 512 * 256, b1, H1);

    // GEMM2: GR = H1 @ [W2_rel | W2_root]  (sum-agg commuted past the GEMM)
    k_gemm2<<<(NNODES + 63) / 64, 256, 0, stream>>>(H1, Bt2, GR);

    // fused aggregation + index terms + bias + leaky-relu + head
    k_agg2h<<<NNODES / 4, 256, 0, stream>>>(
        row_start, srcs, GR, W2_rel + 256 * 64, W2_root + 256 * 64, b2,
        Wp, bp, Wr, br, out);
}

// Round 12
// 321.189 us; speedup vs baseline: 1.3852x; 1.0454x over previous
//
#include <hip/hip_runtime.h>

#define NNODES 50000
#define NEDGES 200000
#define NSCANB ((NNODES + 255) / 256)   // 196 scan blocks

typedef short  bf16x8 __attribute__((ext_vector_type(8)));
typedef float  f32x4  __attribute__((ext_vector_type(4)));
typedef unsigned int u32x4 __attribute__((ext_vector_type(4)));

__device__ __forceinline__ unsigned short f2bf(float f) {
    union { float f; unsigned int u; } c; c.f = f;
    unsigned int r = c.u + 0x7fffu + ((c.u >> 16) & 1u);
    return (unsigned short)(r >> 16);
}
__device__ __forceinline__ float bf2f(unsigned short h) {
    union { unsigned int u; float f; } c; c.u = ((unsigned int)h) << 16;
    return c.f;
}
__device__ __forceinline__ float bflo(unsigned int v) {
    union { unsigned int u; float f; } c; c.u = v << 16;
    return c.f;
}
__device__ __forceinline__ float bfhi(unsigned int v) {
    union { unsigned int u; float f; } c; c.u = v & 0xffff0000u;
    return c.f;
}

// ---------------- fused prep + edge count (wide grid-stride) ----------------
// deg[] is zeroed by hipMemsetAsync before this launch.
// Bt2 layout [128][256]: rows 0..63 = W2_rel columns, rows 64..127 = W2_root
// columns (k<256 only; index rows applied in k_agg2h).
#define PREP_B1 (256 * 1024)
#define PREP_B2 (128 * 256)
#define PREP_XC (NNODES * 64)
__global__ __launch_bounds__(256) void k_prepcount(const float* __restrict__ x,
                                                   const float* __restrict__ W1_rel,
                                                   const float* __restrict__ W1_root,
                                                   const float* __restrict__ W2_rel,
                                                   const float* __restrict__ W2_root,
                                                   const int* __restrict__ ei,
                                                   int* __restrict__ deg,
                                                   unsigned short* __restrict__ Bt1,
                                                   unsigned short* __restrict__ Bt2,
                                                   unsigned short* __restrict__ xb) {
    const int gtid = blockIdx.x * 256 + threadIdx.x;
    const int GS = gridDim.x * 256;
    for (int e = gtid; e < NEDGES; e += GS) atomicAdd(&deg[ei[NEDGES + e]], 1);
    for (int i = gtid; i < PREP_B1; i += GS) {
        int n = i >> 10, k = i & 1023;
        float v = (k < 512) ? W1_rel[k * 256 + n] : W1_root[(k - 512) * 256 + n];
        Bt1[i] = f2bf(v);
    }
    for (int i = gtid; i < PREP_B2; i += GS) {
        int n = i >> 8, k = i & 255;
        float v = (n < 64) ? W2_rel[k * 64 + n] : W2_root[k * 64 + (n - 64)];
        Bt2[i] = f2bf(v);
    }
    for (int i = gtid; i < PREP_XC; i += GS) {
        int n = i >> 6, c8 = (i & 63) * 8;
        const float* xp = x + (size_t)n * 512 + c8;
        float4 a = *(const float4*)xp;
        float4 bb = *(const float4*)(xp + 4);
        unsigned short o[8];
        o[0] = f2bf(a.x); o[1] = f2bf(a.y); o[2] = f2bf(a.z); o[3] = f2bf(a.w);
        o[4] = f2bf(bb.x); o[5] = f2bf(bb.y); o[6] = f2bf(bb.z); o[7] = f2bf(bb.w);
        *(u32x4*)(xb + (size_t)n * 512 + c8) = *(const u32x4*)o;
    }
}

// ---------------- CSR scan: block-local exclusive ----------------
__global__ __launch_bounds__(256) void k_scanA(const int* __restrict__ deg,
                                               int* __restrict__ rs,
                                               int* __restrict__ partials) {
    __shared__ int sm[256];
    int t = threadIdx.x, i = blockIdx.x * 256 + t;
    int v = (i < NNODES) ? deg[i] : 0;
    sm[t] = v;
    __syncthreads();
#pragma unroll
    for (int off = 1; off < 256; off <<= 1) {
        int u = (t >= off) ? sm[t - off] : 0;
        __syncthreads();
        sm[t] += u;
        __syncthreads();
    }
    if (i < NNODES) rs[i] = sm[t] - v;
    if (t == 255) partials[blockIdx.x] = sm[255];
}

// fused scanB+scanC: each block reduces partials[0..b-1] itself (196 ints)
__global__ __launch_bounds__(256) void k_scanC2(int* __restrict__ rs,
                                                const int* __restrict__ partials,
                                                int* __restrict__ cursor) {
    __shared__ int sm[256];
    int t = threadIdx.x, b = blockIdx.x;
    sm[t] = (t < b && t < NSCANB) ? partials[t] : 0;
    __syncthreads();
#pragma unroll
    for (int off = 128; off; off >>= 1) {
        if (t < off) sm[t] += sm[t + off];
        __syncthreads();
    }
    int off0 = sm[0];
    int i = b * 256 + t;
    if (i < NNODES) {
        int rv = rs[i] + off0;
        rs[i] = rv;
        cursor[i] = rv;
    }
    if (i == 0) rs[NNODES] = NEDGES;
}

__global__ void k_scatter(const int* __restrict__ ei, int* __restrict__ cursor,
                          int* __restrict__ srcs) {
    int e = blockIdx.x * 256 + threadIdx.x;
    if (e < NEDGES) {
        int d = ei[NEDGES + e];
        int p = atomicAdd(&cursor[d], 1);
        srcs[p] = ei[e];
    }
}

// ---------------- softmax aggregation (layer 1): wave-per-node -------------
__global__ __launch_bounds__(256) void k_agg1(const unsigned short* __restrict__ xb,
                                              const int* __restrict__ rs,
                                              const int* __restrict__ srcs,
                                              unsigned short* __restrict__ AggBuf) {
    int wv = threadIdx.x >> 6;
    int lane = threadIdx.x & 63;
    int n = blockIdx.x * 4 + wv;
    int e0 = rs[n], e1 = rs[n + 1];
    float nu[8], de[8];
#pragma unroll
    for (int j = 0; j < 8; ++j) { nu[j] = 0.f; de[j] = 0.f; }

    auto accum = [&](u32x4 r) {
#pragma unroll
        for (int p = 0; p < 4; ++p) {
            float v0 = bflo(r[p]), v1 = bfhi(r[p]);
            float E0 = __expf(v0), E1 = __expf(v1);
            de[2 * p] += E0; nu[2 * p] += E0 * v0;
            de[2 * p + 1] += E1; nu[2 * p + 1] += E1 * v1;
        }
    };

    int e = e0;
    for (; e + 3 < e1; e += 4) {
        int s0 = srcs[e], s1 = srcs[e + 1], s2 = srcs[e + 2], s3 = srcs[e + 3];
        u32x4 r0 = *(const u32x4*)(xb + (size_t)s0 * 512 + lane * 8);
        u32x4 r1 = *(const u32x4*)(xb + (size_t)s1 * 512 + lane * 8);
        u32x4 r2 = *(const u32x4*)(xb + (size_t)s2 * 512 + lane * 8);
        u32x4 r3 = *(const u32x4*)(xb + (size_t)s3 * 512 + lane * 8);
        accum(r0); accum(r1); accum(r2); accum(r3);
    }
    if (e + 1 < e1) {
        int s0 = srcs[e], s1 = srcs[e + 1];
        u32x4 r0 = *(const u32x4*)(xb + (size_t)s0 * 512 + lane * 8);
        u32x4 r1 = *(const u32x4*)(xb + (size_t)s1 * 512 + lane * 8);
        accum(r0); accum(r1);
        e += 2;
    }
    if (e < e1) {
        u32x4 r0 = *(const u32x4*)(xb + (size_t)srcs[e] * 512 + lane * 8);
        accum(r0);
    }
    unsigned short o[8];
#pragma unroll
    for (int j = 0; j < 8; ++j) o[j] = f2bf(nu[j] / fmaxf(de[j], 1e-16f));
    *(u32x4*)(AggBuf + (size_t)n * 512 + lane * 8) = *(const u32x4*)o;
}

// ---------------- GEMM1+GEMM2 fused: 64x256 tile, H1 never materialized -----
// Phase 1: h1 = lrelu([AggBuf|xb] @ Bt1^T + idx terms + b1), 64x256 per block,
//   counted-vmcnt double-buffer (5 loads/thread/stage -> vmcnt(5)).
// Phase 2: h1 tile -> LDS (XOR-swizzled), GR[64x128] = h1 @ Bt2^T from LDS,
//   Bt2 (64KB, L2-hot) staged 16KB per K-chunk. Saves the 51MB H1 round-trip.
// LDS carve (80KB): phase1 As[2]@0 (16K) Bs[2]@16K (64K);
//   phase2 h1t@0 (32K), B2s@32K (16K), s1t@48K (256B).
__global__ __launch_bounds__(512) void k_gemm12(const unsigned short* __restrict__ A1,
                                                const unsigned short* __restrict__ A2,
                                                const unsigned short* __restrict__ Bt,
                                                const unsigned short* __restrict__ Bt2,
                                                const int* __restrict__ rs,
                                                const int* __restrict__ srcs,
                                                const float* __restrict__ r1,
                                                const float* __restrict__ r2,
                                                const float* __restrict__ bias,
                                                unsigned short* __restrict__ GR) {
    constexpr int BM = 64, BK = 64;
    __shared__ __align__(16) unsigned char lds_raw[81920];
    unsigned short* AsB[2] = {(unsigned short*)(lds_raw),
                              (unsigned short*)(lds_raw + 8192)};
    unsigned short* BsB[2] = {(unsigned short*)(lds_raw + 16384),
                              (unsigned short*)(lds_raw + 49152)};
    unsigned short* h1t = (unsigned short*)(lds_raw);            // 64 x 256
    unsigned short* B2s = (unsigned short*)(lds_raw + 32768);    // 128 x 64
    float* s1t = (float*)(lds_raw + 49152);                      // 64 floats

    const int tid = threadIdx.x;
    const int w = tid >> 6;        // 0..7
    const int lane = tid & 63;
    const int lm = lane & 15;
    const int quad = lane >> 4;
    const int wr = w >> 2;         // 0..1
    const int wc = w & 3;          // 0..3
    const int rowbase = blockIdx.x * BM;
    const int wrow = wr * 32;
    const int wcol = wc * 64;
    const int rsub = lane >> 3;
    const int csw = (lane & 7) ^ rsub;

    f32x4 acc[2][4];
#pragma unroll
    for (int mi = 0; mi < 2; ++mi)
#pragma unroll
        for (int ni = 0; ni < 4; ++ni) acc[mi][ni] = (f32x4){0.f, 0.f, 0.f, 0.f};

    // 5 global_load_lds per thread per stage (1 A + 4 B)
    auto stage = [&](unsigned short* Asb, unsigned short* Bsb, int kt) {
        const unsigned short* Ab = (kt < 512) ? A1 : A2;
        int kof = (kt < 512) ? kt : kt - 512;
        {
            int r = w * 8;
            int gr = rowbase + r + rsub;
            if (gr >= NNODES) gr = NNODES - 1;
            const unsigned short* gp = Ab + (size_t)gr * 512 + kof + csw * 8;
            __builtin_amdgcn_global_load_lds(
                (const __attribute__((address_space(1))) void*)gp,
                (__attribute__((address_space(3))) void*)(Asb + r * BK), 16, 0, 0);
        }
#pragma unroll
        for (int l = 0; l < 4; ++l) {
            int r = w * 32 + l * 8;
            const unsigned short* gp = Bt + (size_t)(r + rsub) * 1024 + kt + csw * 8;
            __builtin_amdgcn_global_load_lds(
                (const __attribute__((address_space(1))) void*)gp,
                (__attribute__((address_space(3))) void*)(Bsb + r * BK), 16, 0, 0);
        }
    };

    auto compute = [&](const unsigned short* Asb, const unsigned short* Bsb) {
#pragma unroll
        for (int kk = 0; kk < BK; kk += 32) {
            const int kidx = (kk >> 3) + quad;
            const int phys = kidx ^ (lm & 7);
            bf16x8 af[2], bfr[4];
#pragma unroll
            for (int mi = 0; mi < 2; ++mi)
                af[mi] = __builtin_bit_cast(bf16x8,
                    *(const u32x4*)(Asb + (wrow + mi * 16 + lm) * BK + phys * 8));
#pragma unroll
            for (int ni = 0; ni < 4; ++ni)
                bfr[ni] = __builtin_bit_cast(bf16x8,
                    *(const u32x4*)(Bsb + (wcol + ni * 16 + lm) * BK + phys * 8));
#pragma unroll
            for (int mi = 0; mi < 2; ++mi)
#pragma unroll
                for (int ni = 0; ni < 4; ++ni)
                    acc[mi][ni] = __builtin_amdgcn_mfma_f32_16x16x32_bf16(
                        af[mi], bfr[ni], acc[mi][ni], 0, 0, 0);
        }
    };

    stage(AsB[0], BsB[0], 0);
#pragma unroll 1
    for (int t = 0; t < 16; t += 2) {
        stage(AsB[1], BsB[1], (t + 1) * BK);
        asm volatile("s_waitcnt vmcnt(5)" ::: "memory");
        __builtin_amdgcn_s_barrier();
        __builtin_amdgcn_sched_barrier(0);
        compute(AsB[0], BsB[0]);
        __builtin_amdgcn_s_barrier();
        if (t + 2 < 16) {
            stage(AsB[0], BsB[0], (t + 2) * BK);
            asm volatile("s_waitcnt vmcnt(5)" ::: "memory");
        } else {
            asm volatile("s_waitcnt vmcnt(0)" ::: "memory");
        }
        __builtin_amdgcn_s_barrier();
        __builtin_amdgcn_sched_barrier(0);
        compute(AsB[1], BsB[1]);
        __builtin_amdgcn_s_barrier();
    }

    // per-row index softmax (threads 0..63)
    if (tid < BM) {
        int grow = rowbase + tid;
        float r_ = 0.f;
        if (grow < NNODES) {
            int e0 = rs[grow], e1 = rs[grow + 1];
            float m = -INFINITY, d = 0.f, q = 0.f;
            for (int e = e0; e < e1; ++e) {
                float v = (float)srcs[e];
                float nm = fmaxf(m, v);
                float sc = __expf(m - nm), ee = __expf(v - nm);
                d = d * sc + ee;
                q = q * sc + ee * v;
                m = nm;
            }
            r_ = q / fmaxf(d, 1e-16f);
        }
        s1t[tid] = r_;
    }
    __syncthreads();

    // h1 epilogue -> LDS (XOR-swizzled: col-block cb stored at cb^(row&7))
#pragma unroll
    for (int ni = 0; ni < 4; ++ni) {
        int c = wcol + ni * 16 + lm;
        float r1v = r1[c], r2v = r2[c], bv = bias[c];
#pragma unroll
        for (int mi = 0; mi < 2; ++mi) {
#pragma unroll
            for (int r = 0; r < 4; ++r) {
                int lrow = wrow + mi * 16 + quad * 4 + r;
                int grow = rowbase + lrow;
                float v = acc[mi][ni][r] + s1t[lrow] * r1v + (float)grow * r2v + bv;
                v = (v >= 0.f) ? v : 0.01f * v;
                int pos = lrow * 256 + (((c >> 3) ^ (lrow & 7)) << 3) + (c & 7);
                h1t[pos] = f2bf(v);
            }
        }
    }
    __syncthreads();

    // phase 2: GR[64x128] = h1 @ Bt2^T (K = 256), Bt2 staged 128x64 per chunk
    const int wr2 = w >> 2, wc2 = w & 3;   // 2 x 4 waves over 64 x 128
    f32x4 acc2[2][2];
#pragma unroll
    for (int mi = 0; mi < 2; ++mi)
#pragma unroll
        for (int ni = 0; ni < 2; ++ni) acc2[mi][ni] = (f32x4){0.f, 0.f, 0.f, 0.f};

#pragma unroll 1
    for (int kt = 0; kt < 256; kt += 64) {
#pragma unroll
        for (int l = 0; l < 2; ++l) {
            int r = w * 16 + l * 8;
            const unsigned short* gp = Bt2 + (size_t)(r + rsub) * 256 + kt + csw * 8;
            __builtin_amdgcn_global_load_lds(
                (const __attribute__((address_space(1))) void*)gp,
                (__attribute__((address_space(3))) void*)(B2s + r * 64), 16, 0, 0);
        }
        __syncthreads();
#pragma unroll
        for (int kk = 0; kk < 64; kk += 32) {
            const int kidx = (kk >> 3) + quad;          // local col-block in chunk
            const int physB = kidx ^ (lm & 7);
            const int cbg = (kt >> 3) + kidx;           // global col-block in h1
            const int physA = cbg ^ (lm & 7);
            bf16x8 af[2], bfr[2];
#pragma unroll
            for (int mi = 0; mi < 2; ++mi)
                af[mi] = __builtin_bit_cast(bf16x8,
                    *(const u32x4*)(h1t + (wr2 * 32 + mi * 16 + lm) * 256 + physA * 8));
#pragma unroll
            for (int ni = 0; ni < 2; ++ni)
                bfr[ni] = __builtin_bit_cast(bf16x8,
                    *(const u32x4*)(B2s + (wc2 * 32 + ni * 16 + lm) * 64 + physB * 8));
#pragma unroll
            for (int mi = 0; mi < 2; ++mi)
#pragma unroll
                for (int ni = 0; ni < 2; ++ni)
                    acc2[mi][ni] = __builtin_amdgcn_mfma_f32_16x16x32_bf16(
                        af[mi], bfr[ni], acc2[mi][ni], 0, 0, 0);
        }
        __syncthreads();
    }

    // GR write (raw, no bias/activation: applied in k_agg2h)
#pragma unroll
    for (int ni = 0; ni < 2; ++ni) {
        int gc = wc2 * 32 + ni * 16 + lm;
#pragma unroll
        for (int mi = 0; mi < 2; ++mi) {
#pragma unroll
            for (int r = 0; r < 4; ++r) {
                int grow = rowbase + wr2 * 32 + mi * 16 + quad * 4 + r;
                if (grow < NNODES)
                    GR[(size_t)grow * 128 + gc] = f2bf(acc2[mi][ni][r]);
            }
        }
    }
}

// ---------------- agg2 + head (fused, wave-per-node) ------------------------
// h2 = sum_{src} G[src] + si*r1 + R[n] + n*r2 + b2, leaky-relu, then the
// 7-output head via butterfly reductions.
__global__ __launch_bounds__(256) void k_agg2h(const int* __restrict__ rs,
                                               const int* __restrict__ srcs,
                                               const unsigned short* __restrict__ GR,
                                               const float* __restrict__ r1,
                                               const float* __restrict__ r2,
                                               const float* __restrict__ bias,
                                               const float* __restrict__ Wp,
                                               const float* __restrict__ bp,
                                               const float* __restrict__ Wr,
                                               const float* __restrict__ br,
                                               float* __restrict__ out) {
    const int wv = threadIdx.x >> 6;
    const int lane = threadIdx.x & 63;
    const int n = blockIdx.x * 4 + wv;
    const int e0 = rs[n], e1 = rs[n + 1];

    float g = 0.f, si = 0.f;
    int e = e0;
    for (; e + 3 < e1; e += 4) {
        int s0 = srcs[e], s1 = srcs[e + 1], s2 = srcs[e + 2], s3 = srcs[e + 3];
        float g0 = bf2f(GR[(size_t)s0 * 128 + lane]);
        float g1 = bf2f(GR[(size_t)s1 * 128 + lane]);
        float g2 = bf2f(GR[(size_t)s2 * 128 + lane]);
        float g3 = bf2f(GR[(size_t)s3 * 128 + lane]);
        g += (g0 + g1) + (g2 + g3);
        si += (float)(s0 + s1) + (float)(s2 + s3);
    }
    if (e + 1 < e1) {
        int s0 = srcs[e], s1 = srcs[e + 1];
        g += bf2f(GR[(size_t)s0 * 128 + lane]) + bf2f(GR[(size_t)s1 * 128 + lane]);
        si += (float)(s0 + s1);
        e += 2;
    }
    if (e < e1) {
        int s0 = srcs[e];
        g += bf2f(GR[(size_t)s0 * 128 + lane]);
        si += (float)s0;
    }

    float h2 = g + si * r1[lane] + bf2f(GR[(size_t)n * 128 + 64 + lane])
             + (float)n * r2[lane] + bias[lane];
    h2 = (h2 >= 0.f) ? h2 : 0.01f * h2;

    float p0 = h2 * Wp[lane * 3 + 0];
    float p1 = h2 * Wp[lane * 3 + 1];
    float p2 = h2 * Wp[lane * 3 + 2];
    float q0 = h2 * Wr[lane * 4 + 0];
    float q1 = h2 * Wr[lane * 4 + 1];
    float q2 = h2 * Wr[lane * 4 + 2];
    float q3 = h2 * Wr[lane * 4 + 3];
#pragma unroll
    for (int m = 1; m < 64; m <<= 1) {
        p0 += __shfl_xor(p0, m);
        p1 += __shfl_xor(p1, m);
        p2 += __shfl_xor(p2, m);
        q0 += __shfl_xor(q0, m);
        q1 += __shfl_xor(q1, m);
        q2 += __shfl_xor(q2, m);
        q3 += __shfl_xor(q3, m);
    }
    const float idx = (float)n;
    p0 += idx * Wp[64 * 3 + 0] + bp[0];
    p1 += idx * Wp[64 * 3 + 1] + bp[1];
    p2 += idx * Wp[64 * 3 + 2] + bp[2];
    q0 += idx * Wr[64 * 4 + 0] + br[0];
    q1 += idx * Wr[64 * 4 + 1] + br[1];
    q2 += idx * Wr[64 * 4 + 2] + br[2];
    q3 += idx * Wr[64 * 4 + 3] + br[3];
    float nrm = fmaxf(sqrtf(q0 * q0 + q1 * q1 + q2 * q2 + q3 * q3), 1e-12f);
    float o = (lane == 0) ? p0 : (lane == 1) ? p1 : (lane == 2) ? p2
            : (lane == 3) ? q0 / nrm : (lane == 4) ? q1 / nrm
            : (lane == 5) ? q2 / nrm : q3 / nrm;
    if (lane < 7) out[(size_t)n * 7 + lane] = o;
}

extern "C" void kernel_launch(void* const* d_in, const int* in_sizes, int n_in,
                              void* d_out, int out_size, void* d_ws, size_t ws_size,
                              hipStream_t stream) {
    const float* x       = (const float*)d_in[0];
    const float* W1_rel  = (const float*)d_in[1];
    const float* b1      = (const float*)d_in[2];
    const float* W1_root = (const float*)d_in[3];
    const float* W2_rel  = (const float*)d_in[4];
    const float* b2      = (const float*)d_in[5];
    const float* W2_root = (const float*)d_in[6];
    const float* Wp      = (const float*)d_in[7];
    const float* bp      = (const float*)d_in[8];
    const float* Wr      = (const float*)d_in[9];
    const float* br      = (const float*)d_in[10];
    const int*   ei      = (const int*)d_in[11];
    float* out = (float*)d_out;

    char* ws = (char*)d_ws;
    size_t off = 0;
    auto alloc = [&](size_t bytes) {
        size_t o = off;
        off = (off + bytes + 255) & ~(size_t)255;
        return (void*)(ws + o);
    };
    int*   deg       = (int*)alloc(NNODES * 4);
    int*   cursor    = (int*)alloc(NNODES * 4);
    int*   row_start = (int*)alloc((NNODES + 1) * 4);
    int*   srcs      = (int*)alloc(NEDGES * 4);
    int*   partials  = (int*)alloc(NSCANB * 4);
    unsigned short* xb     = (unsigned short*)alloc((size_t)NNODES * 512 * 2);
    unsigned short* AggBuf = (unsigned short*)alloc((size_t)NNODES * 512 * 2);
    unsigned short* GR     = (unsigned short*)alloc((size_t)NNODES * 128 * 2);
    unsigned short* Bt1    = (unsigned short*)alloc(256 * 1024 * 2);
    unsigned short* Bt2    = (unsigned short*)alloc(128 * 256 * 2);

    hipMemsetAsync(deg, 0, NNODES * 4, stream);

    k_prepcount<<<2048, 256, 0, stream>>>(
        x, W1_rel, W1_root, W2_rel, W2_root, ei, deg, Bt1, Bt2, xb);

    k_scanA<<<NSCANB, 256, 0, stream>>>(deg, row_start, partials);
    k_scanC2<<<NSCANB, 256, 0, stream>>>(row_start, partials, cursor);
    k_scatter<<<(NEDGES + 255) / 256, 256, 0, stream>>>(ei, cursor, srcs);

    k_agg1<<<NNODES / 4, 256, 0, stream>>>(xb, row_start, srcs, AggBuf);

    // fused GEMM1+GEMM2: [AggBuf | xb] @ Bt1^T -> h1 (LDS only) -> GR
    k_gemm12<<<(NNODES + 63) / 64, 512, 0, stream>>>(
        AggBuf, xb, Bt1, Bt2, row_start, srcs,
        W1_rel + 512 * 256, W1_root + 512 * 256, b1, GR);

    // fused aggregation + index terms + bias + leaky-relu + head
    k_agg2h<<<NNODES / 4, 256, 0, stream>>>(
        row_start, srcs, GR, W2_rel + 256 * 64, W2_root + 256 * 64, b2,
        Wp, bp, Wr, br, out);
}